// Round 18
// baseline (290.258 us; speedup 1.0000x reference)
//
#include <hip/hip_runtime.h>
#include <cstddef>
#include <cstdint>

#define BB 4
#define HH 8
#define HEADD 64
#define DIMM 512
#define XLL 1024
#define KLL 256
#define BHH (BB*HH)

typedef __attribute__((ext_vector_type(8))) short bf16x8;
typedef __attribute__((ext_vector_type(8))) unsigned short u16x8;
typedef __attribute__((ext_vector_type(4))) float f32x4;
typedef unsigned short u16;
typedef unsigned long long u64;

__device__ __forceinline__ u16 f2b(float f) {
    unsigned int u = __builtin_bit_cast(unsigned int, f);
    u = u + 0x7fffu + ((u >> 16) & 1u);
    return (u16)(u >> 16);
}
__device__ __forceinline__ float b2f(u16 h) {
    unsigned int u = ((unsigned int)h) << 16;
    return __builtin_bit_cast(float, u);
}
__device__ __forceinline__ f32x4 mfma16(bf16x8 a, bf16x8 b, f32x4 c) {
    return __builtin_amdgcn_mfma_f32_16x16x32_bf16(a, b, c, 0, 0, 0);
}
__device__ __forceinline__ float wred_max(float v) {
    #pragma unroll
    for (int o = 1; o < 64; o <<= 1) v = fmaxf(v, __shfl_xor(v, o, 64));
    return v;
}
__device__ __forceinline__ float wred_sum(float v) {
    #pragma unroll
    for (int o = 1; o < 64; o <<= 1) v += __shfl_xor(v, o, 64);
    return v;
}

// Fragment-order layout (element == byte index for u8 variant):
//   E(bh,x,k) = ((bh*64 + (x>>4))*8 + (k>>5))*512
//             + (((x>>2)&3)*16 + (k&15))*8 + ((k>>4)&1)*4 + (x&3)

// ---------------------------------------------------------------------------
// Merged prep: blocks [0,3072) = 6 weight transposes (f32 [K][N]->bf16 [N][K]);
// blocks [3072,19456): mask prep. z<32: i_att -> iattT8 (u8 [bh,k,x]) +
// iattB8 (u8 fragment order). z>=32: cross -> crossB8 (u8 fragment order).
// ---------------------------------------------------------------------------
__global__ __launch_bounds__(256) void prep_all_k(
    const float* __restrict__ s0, const float* __restrict__ s1,
    const float* __restrict__ s2, const float* __restrict__ s3,
    const float* __restrict__ s4, const float* __restrict__ s5,
    u16* __restrict__ d0, u16* __restrict__ d1, u16* __restrict__ d2,
    u16* __restrict__ d3, u16* __restrict__ d4, u16* __restrict__ d5,
    const int* __restrict__ i_att, unsigned char* __restrict__ iattT8,
    unsigned char* __restrict__ iattB8,
    const int* __restrict__ cross, unsigned char* __restrict__ crossB8)
{
    const int id = blockIdx.x;
    if (id < 3072) {
        __shared__ float t[32][33];
        const float* W; u16* Wt; int N, bx, by;
        if (id < 2304) {
            int which = id / 768, local = id - which * 768;
            W = which == 0 ? s0 : (which == 1 ? s1 : s2);
            Wt = which == 0 ? d0 : (which == 1 ? d1 : d2);
            N = 1536; bx = local % 48; by = local / 48;
        } else {
            int which = (id - 2304) / 256, local = (id - 2304) % 256;
            W = which == 0 ? s3 : (which == 1 ? s4 : s5);
            Wt = which == 0 ? d3 : (which == 1 ? d4 : d5);
            N = 512; bx = local % 16; by = local / 16;
        }
        const int K = 512;
        int tx = threadIdx.x & 31, ty = threadIdx.x >> 5;
        #pragma unroll
        for (int r = ty; r < 32; r += 8)
            t[r][tx] = W[(size_t)(by * 32 + r) * N + bx * 32 + tx];
        __syncthreads();
        #pragma unroll
        for (int r = ty; r < 32; r += 8)
            Wt[(size_t)(bx * 32 + r) * K + by * 32 + tx] = f2b(t[tx][r]);
        return;
    }
    const int id2 = id - 3072;
    const int xt = id2 & 31, kt = (id2 >> 5) & 7, z = id2 >> 8;
    const int bh = z & 31;
    const int tid = threadIdx.x;
    const int sl = tid >> 7, rem = tid & 127, l = rem >> 1, nilow = rem & 1;
    const int lg = l >> 4, lr_ = l & 15;
    const int xl0 = sl * 16 + lg * 4, kl = nilow * 16 + lr_;
    if (z < 32) {
        __shared__ unsigned char t8[32][33];   // [x][k]
        const int tx = tid & 31, ty = tid >> 5;
        #pragma unroll
        for (int r = ty; r < 32; r += 8)
            t8[r][tx] = (unsigned char)(i_att[((size_t)bh * 1024 + xt * 32 + r) * 256 + kt * 32 + tx] != 0);
        __syncthreads();
        #pragma unroll
        for (int r = ty; r < 32; r += 8)
            iattT8[((size_t)bh * 256 + kt * 32 + r) * 1024 + xt * 32 + tx] = t8[tx][r];
        uchar4 o;
        o.x = t8[xl0 + 0][kl]; o.y = t8[xl0 + 1][kl];
        o.z = t8[xl0 + 2][kl]; o.w = t8[xl0 + 3][kl];
        size_t eb = (((size_t)bh * 64 + xt * 2 + sl) * 8 + kt) * 512 + (size_t)l * 8 + nilow * 4;
        *reinterpret_cast<uchar4*>(iattB8 + eb) = o;
    } else {
        const int kg = kt * 32 + kl;
        uchar4 o;
        o.x = (unsigned char)(cross[((size_t)bh * 1024 + xt * 32 + xl0 + 0) * 256 + kg] != 0);
        o.y = (unsigned char)(cross[((size_t)bh * 1024 + xt * 32 + xl0 + 1) * 256 + kg] != 0);
        o.z = (unsigned char)(cross[((size_t)bh * 1024 + xt * 32 + xl0 + 2) * 256 + kg] != 0);
        o.w = (unsigned char)(cross[((size_t)bh * 1024 + xt * 32 + xl0 + 3) * 256 + kg] != 0);
        size_t eb = (((size_t)bh * 64 + xt * 2 + sl) * 8 + kt) * 512 + (size_t)l * 8 + nilow * 4;
        *reinterpret_cast<uchar4*>(crossB8 + eb) = o;
    }
}

// ---------------------------------------------------------------------------
// main orientation: block per (b,k); reads polar row once, loops 8 heads.
// ---------------------------------------------------------------------------
__global__ __launch_bounds__(256) void main_ori_k8(
    const u16* __restrict__ S, const int* __restrict__ polar,
    int* __restrict__ MO)
{
    const int blk = blockIdx.x;          // b*256 + k
    const int b = blk >> 8, k = blk & 255;
    const int tid = threadIdx.x;
    const int wave = tid >> 6, lane = tid & 63;
    const int c = tid * 4;
    int4 p4 = *reinterpret_cast<const int4*>(polar + ((size_t)b * 256 + k) * 1024 + c);
    int pp[4] = { p4.x, p4.y, p4.z, p4.w };
    #pragma unroll
    for (int j = 0; j < 4; ++j) { int p = pp[j]; pp[j] = p < 0 ? 0 : (p > 7 ? 7 : p); }
    __shared__ float sred[4][8];
    for (int h = 0; h < 8; ++h) {
        const int bh = b * 8 + h;
        ushort4 sv = *reinterpret_cast<const ushort4*>(S + ((size_t)bh * 256 + k) * 1024 + c);
        float av[4] = { fabsf(b2f(sv.x)), fabsf(b2f(sv.y)), fabsf(b2f(sv.z)), fabsf(b2f(sv.w)) };
        float bins[8] = {};
        #pragma unroll
        for (int j = 0; j < 4; ++j) {
            #pragma unroll
            for (int o = 0; o < 8; ++o) bins[o] += (pp[j] == o) ? av[j] : 0.0f;
        }
        #pragma unroll
        for (int o = 0; o < 8; ++o) bins[o] = wred_sum(bins[o]);
        if (lane == 0) {
            #pragma unroll
            for (int o = 0; o < 8; ++o) sred[wave][o] = bins[o];
        }
        __syncthreads();
        if (tid == 0) {
            int best = 0; float bv = -1.0f;
            #pragma unroll
            for (int o = 0; o < 8; ++o) {
                float s = sred[0][o] + sred[1][o] + sred[2][o] + sred[3][o];
                if (s > bv) { bv = s; best = o; }
            }
            MO[bh * 256 + k] = best;
        }
        __syncthreads();
    }
}

// ---------------------------------------------------------------------------
// Combined bias build (after MO): biasF fragment order (-1e9) + bias1 [bh,k,x] (-1e6)
// ---------------------------------------------------------------------------
__global__ __launch_bounds__(256) void bias_build_k(
    const int* __restrict__ rd, const int* __restrict__ polar,
    const int* __restrict__ att, const float* __restrict__ dis,
    const float* __restrict__ pemb, const int* __restrict__ MO,
    u16* __restrict__ biasF, u16* __restrict__ bias1)
{
    const int b = blockIdx.z;
    const int xt = blockIdx.x * 32, kt = blockIdx.y * 32;
    const int tid = threadIdx.x;
    __shared__ float dsh[528];
    __shared__ int rds[32][33];   // [x][k]
    __shared__ int pls[32][33];
    __shared__ u16 bt[32][33];    // -1e6 variant [x][k]
    for (int i = tid; i < 528; i += 256) dsh[i] = dis[i];
    const int tx = tid & 31, ty = tid >> 5;
    #pragma unroll
    for (int r = ty; r < 32; r += 8) {
        size_t src = ((size_t)b * 256 + kt + r) * 1024 + xt + tx;  // rd[b,k,x]
        rds[tx][r] = rd[src];
        int p = polar[src]; pls[tx][r] = p < 0 ? 0 : (p > 7 ? 7 : p);
    }
    float pe[8];
    #pragma unroll
    for (int o = 0; o < 8; ++o) pe[o] = pemb[o];
    __syncthreads();
    const int sl = tid >> 7, rem = tid & 127, l = rem >> 1, nilow = rem & 1;
    const int lg = l >> 4, lr_ = l & 15;
    const int xl0 = sl * 16 + lg * 4, kl = nilow * 16 + lr_;
    const int kg = kt + kl;
    const u16 NEG9 = f2b(-1e9f), NEG6 = f2b(-1e6f);
    for (int h = 0; h < 8; ++h) {
        const int bh = b * 8 + h;
        int mo = MO[bh * 256 + kg];
        u16 o9[4];
        #pragma unroll
        for (int j = 0; j < 4; ++j) {
            int xl = xl0 + j;
            int mm = att[((size_t)bh * 1024 + xt + xl) * 256 + kg];
            float v = dsh[rds[xl][kl] * 8 + h] + pe[(pls[xl][kl] - mo + 8) & 7];
            u16 vb = f2b(v);
            o9[j] = mm ? NEG9 : vb;
            bt[xl][kl] = mm ? NEG6 : vb;
        }
        size_t eb = (((size_t)bh * 64 + (xt >> 4) + sl) * 8 + (kt >> 5)) * 512 + (size_t)l * 8 + nilow * 4;
        ushort4 ov; ov.x = o9[0]; ov.y = o9[1]; ov.z = o9[2]; ov.w = o9[3];
        *reinterpret_cast<ushort4*>(biasF + eb) = ov;
        __syncthreads();
        const int k_ = tid >> 3, x4 = (tid & 7) * 4;
        ushort4 o2;
        o2.x = bt[x4 + 0][k_]; o2.y = bt[x4 + 1][k_];
        o2.z = bt[x4 + 2][k_]; o2.w = bt[x4 + 3][k_];
        *reinterpret_cast<ushort4*>(bias1 + ((size_t)bh * 256 + kt + k_) * 1024 + xt + x4) = o2;
        __syncthreads();
    }
}

// ---------------------------------------------------------------------------
// Software-pipelined 128x128 staged MFMA core. AT = float (cast fused at
// staging) or u16. Optional A2 (bf16): summed into A at staging (runtime).
// ---------------------------------------------------------------------------
template<typename AT>
__device__ __forceinline__ void gemm_core_128(
    const AT* __restrict__ A, const AT* __restrict__ A2,
    const u16* __restrict__ Wt,
    int rb, int cb, short* Asl, short* Bsl, f32x4 (&acc)[4][4])
{
    constexpr bool F32 = sizeof(AT) == 4;
    const int tid = threadIdx.x;
    const int w = tid >> 6, lane = tid & 63;
    const int lr = lane & 15, lk = (lane >> 4) * 8;
    const int wr = (w >> 1) * 64, wc = (w & 1) * 64;
    const int srow = tid >> 3, skc = (tid & 7) * 8;
    const AT* gA = A + (size_t)(rb + srow) * 512 + skc;
    const AT* gA2 = A2 ? A2 + (size_t)(rb + srow) * 512 + skc : nullptr;
    const u16* gB = Wt + (size_t)(cb + srow) * 512 + skc;
    float4 ral[4], rah[4];
    bf16x8 rab[4], rab2[4], rw[4];
    #pragma unroll
    for (int it = 0; it < 4; ++it) {
        if constexpr (F32) {
            ral[it] = *reinterpret_cast<const float4*>(gA + (size_t)it * 32 * 512);
            rah[it] = *reinterpret_cast<const float4*>(gA + (size_t)it * 32 * 512 + 4);
        } else {
            rab[it] = *reinterpret_cast<const bf16x8*>(gA + (size_t)it * 32 * 512);
            if (gA2) rab2[it] = *reinterpret_cast<const bf16x8*>(gA2 + (size_t)it * 32 * 512);
        }
        rw[it] = *reinterpret_cast<const bf16x8*>(gB + (size_t)it * 32 * 512);
    }
    for (int t = 0; t < 8; ++t) {
        #pragma unroll
        for (int it = 0; it < 4; ++it) {
            if constexpr (F32) {
                u16x8 o;
                o[0] = f2b(ral[it].x); o[1] = f2b(ral[it].y);
                o[2] = f2b(ral[it].z); o[3] = f2b(ral[it].w);
                o[4] = f2b(rah[it].x); o[5] = f2b(rah[it].y);
                o[6] = f2b(rah[it].z); o[7] = f2b(rah[it].w);
                *reinterpret_cast<u16x8*>(&Asl[(it * 32 + srow) * 72 + skc]) = o;
            } else {
                if (gA2) {
                    u16x8 o;
                    #pragma unroll
                    for (int e = 0; e < 8; ++e)
                        o[e] = f2b(b2f((u16)rab[it][e]) + b2f((u16)rab2[it][e]));
                    *reinterpret_cast<u16x8*>(&Asl[(it * 32 + srow) * 72 + skc]) = o;
                } else {
                    *reinterpret_cast<bf16x8*>(&Asl[(it * 32 + srow) * 72 + skc]) = rab[it];
                }
            }
            *reinterpret_cast<bf16x8*>(&Bsl[(it * 32 + srow) * 72 + skc]) = rw[it];
        }
        if (t < 7) {
            const int k0 = (t + 1) * 64;
            #pragma unroll
            for (int it = 0; it < 4; ++it) {
                if constexpr (F32) {
                    ral[it] = *reinterpret_cast<const float4*>(gA + k0 + (size_t)it * 32 * 512);
                    rah[it] = *reinterpret_cast<const float4*>(gA + k0 + (size_t)it * 32 * 512 + 4);
                } else {
                    rab[it] = *reinterpret_cast<const bf16x8*>(gA + k0 + (size_t)it * 32 * 512);
                    if (gA2) rab2[it] = *reinterpret_cast<const bf16x8*>(gA2 + k0 + (size_t)it * 32 * 512);
                }
                rw[it] = *reinterpret_cast<const bf16x8*>(gB + k0 + (size_t)it * 32 * 512);
            }
        }
        __syncthreads();
        #pragma unroll
        for (int ks = 0; ks < 2; ++ks) {
            bf16x8 af[4], bf_[4];
            #pragma unroll
            for (int mi = 0; mi < 4; ++mi)
                af[mi] = *reinterpret_cast<const bf16x8*>(&Asl[(wr + mi * 16 + lr) * 72 + ks * 32 + lk]);
            #pragma unroll
            for (int ni = 0; ni < 4; ++ni)
                bf_[ni] = *reinterpret_cast<const bf16x8*>(&Bsl[(wc + ni * 16 + lr) * 72 + ks * 32 + lk]);
            #pragma unroll
            for (int mi = 0; mi < 4; ++mi)
                #pragma unroll
                for (int ni = 0; ni < 4; ++ni)
                    acc[mi][ni] = mfma16(af[mi], bf_[ni], acc[mi][ni]);
        }
        __syncthreads();
    }
}

// ---------------------------------------------------------------------------
// QKV GEMM body with coalesced epilogues. q/k: restage via LDS [128][136],
// then 8 lanes cover a 128B row run (full cachelines). v: LDS transpose then
// 8-threads-per-row 16B writes.
// ---------------------------------------------------------------------------
template<typename AT>
__device__ __forceinline__ void qkv_body(
    const AT* __restrict__ A, const u16* __restrict__ Wt,
    u16* __restrict__ qb, u16* __restrict__ kb, u16* __restrict__ vt,
    int sl, int rb, int cb)
{
    __shared__ __align__(16) short Ls[2 * 128 * 72];
    short* Asl = Ls;
    short* Bsl = Ls + 128 * 72;
    f32x4 acc[4][4] = {};
    gemm_core_128<AT>(A, nullptr, Wt, rb, cb, Asl, Bsl, acc);
    const int tid = threadIdx.x;
    const int wave = tid >> 6, lane = tid & 63;
    const int lr = lane & 15, lg = lane >> 4;
    const int wr = (wave >> 1) * 64, wc = (wave & 1) * 64;
    const int seq = 1 << sl, smask = seq - 1;
    if (cb < 1024) {
        const float scl = (cb < 512) ? 0.125f : 1.0f;
        #pragma unroll
        for (int mi = 0; mi < 4; ++mi)
            #pragma unroll
            for (int ni = 0; ni < 4; ++ni) {
                int row = wr + mi * 16 + lg * 4;
                int col = wc + ni * 16 + lr;
                f32x4 v = acc[mi][ni];
                #pragma unroll
                for (int j = 0; j < 4; ++j)
                    Ls[(row + j) * 136 + col] = (short)f2b(v[j] * scl);
            }
        __syncthreads();
        u16* dst = (cb < 512) ? qb : kb;
        if (dst) {
            const int cbase = (cb < 512) ? cb : cb - 512;
            #pragma unroll
            for (int p = 0; p < 8; ++p) {
                int slot = p * 256 + tid;
                int row = slot >> 4;
                int half = (slot >> 3) & 1;
                int inner = slot & 7;
                int m = rb + row;
                int bb = m >> sl, n = m & smask;
                int cg = cbase + half * 64;
                int h = cg >> 6;
                u16x8 val = *reinterpret_cast<u16x8*>(&Ls[row * 136 + half * 64 + inner * 8]);
                *reinterpret_cast<u16x8*>(
                    &dst[(((size_t)bb * HH + h) * seq + n) * 64 + inner * 8]) = val;
            }
        }
    } else {
        #pragma unroll
        for (int mi = 0; mi < 4; ++mi)
            #pragma unroll
            for (int ni = 0; ni < 4; ++ni) {
                int col = wc + ni * 16 + lr;
                int row0 = wr + mi * 16 + lg * 4;
                f32x4 v = acc[mi][ni];
                #pragma unroll
                for (int j = 0; j < 4; ++j)
                    Ls[col * 136 + row0 + j] = (short)f2b(v[j]);
            }
        __syncthreads();
        const int bb = rb >> sl, n0 = rb & smask;
        #pragma unroll
        for (int p = 0; p < 4; ++p) {
            int slot = p * 256 + tid;
            int col = slot >> 3;
            int inner = slot & 7;
            int dg = (cb - 1024) + col;
            int h = dg >> 6, d = dg & 63;
            u16* vrow = vt + ((((size_t)bb * HH + h) * 64 + d) << sl) + n0;
            u16x8 v0 = *reinterpret_cast<u16x8*>(&Ls[col * 136 + inner * 8]);
            u16x8 v1 = *reinterpret_cast<u16x8*>(&Ls[col * 136 + 64 + inner * 8]);
            *reinterpret_cast<u16x8*>(vrow + inner * 8) = v0;
            *reinterpret_cast<u16x8*>(vrow + 64 + inner * 8) = v1;
        }
    }
}

// All 4 first-stage QKV GEMMs (f32 input, cast fused): 960 blocks, XCD swizzle
__global__ __launch_bounds__(256, 3) void gemm_qkv_all_k(
    const float* __restrict__ A0, const float* __restrict__ A1,
    const float* __restrict__ A2, const float* __restrict__ A3,
    const u16* __restrict__ W01, const u16* __restrict__ W23,
    u16* q0, u16* k0, u16* v0, u16* q1, u16* k1, u16* v1,
    u16* q2, u16* k2, u16* v2, u16* q3, u16* k3, u16* v3)
{
    const int lin = blockIdx.x;
    const int swz = (lin & 7) * 120 + (lin >> 3);
    const int x = swz % 12, y = swz / 12;
    const float* A; const u16* Wt; u16 *qb, *kb, *vt; int sl, ry;
    if (y < 32)      { A = A0; Wt = W01; qb = q0; kb = k0; vt = v0; sl = 10; ry = y; }
    else if (y < 40) { A = A1; Wt = W01; qb = q1; kb = k1; vt = v1; sl = 8;  ry = y - 32; }
    else if (y < 72) { A = A2; Wt = W23; qb = q2; kb = k2; vt = v2; sl = 10; ry = y - 40; }
    else             { A = A3; Wt = W23; qb = q3; kb = k3; vt = v3; sl = 8;  ry = y - 72; }
    qkv_body<float>(A, Wt, qb, kb, vt, sl, ry * 128, x * 128);
}

// Second-stage QKV GEMM (IKOUT, bf16 input): only k/v columns (x offset +4)
__global__ __launch_bounds__(256, 3) void gemm_qkv2_k(
    const u16* __restrict__ A, const u16* __restrict__ Wt,
    u16* kb, u16* vt)
{
    qkv_body<u16>(A, Wt, nullptr, kb, vt, 8, blockIdx.y * 128, (blockIdx.x + 4) * 128);
}

// ---------------------------------------------------------------------------
// Proj GEMM body (pipelined core, bf16 A, optional A2 summed) + bias epilogue
// ---------------------------------------------------------------------------
template<bool OUTBF>
__device__ __forceinline__ void proj_body(
    const u16* __restrict__ A, const u16* __restrict__ A2,
    const u16* __restrict__ Wt,
    const float* __restrict__ bias, float bscale, void* __restrict__ outp,
    int rb, int cb)
{
    __shared__ __align__(16) short Ls[2 * 128 * 72];
    f32x4 acc[4][4] = {};
    gemm_core_128<u16>(A, A2, Wt, rb, cb, Ls, Ls + 128 * 72, acc);
    const int tid = threadIdx.x;
    const int wave = tid >> 6, lane = tid & 63;
    const int lr = lane & 15;
    const int wr = (wave >> 1) * 64, wc = (wave & 1) * 64;
    #pragma unroll
    for (int mi = 0; mi < 4; ++mi) {
        int m0 = rb + wr + mi * 16 + (lane >> 4) * 4;
        #pragma unroll
        for (int ni = 0; ni < 4; ++ni) {
            int c = cb + wc + ni * 16 + lr;
            float bv = bscale * bias[c];
            f32x4 v = acc[mi][ni];
            #pragma unroll
            for (int j = 0; j < 4; ++j) {
                size_t o = (size_t)(m0 + j) * 512 + c;
                if (OUTBF) reinterpret_cast<u16*>(outp)[o] = f2b(v[j] + bv);
                else       reinterpret_cast<float*>(outp)[o] = v[j] + bv;
            }
        }
    }
}

// single proj (IKOUT, bf16 out)
__global__ __launch_bounds__(256, 3) void gemm_proj_bf16_k(
    const u16* __restrict__ A, const u16* __restrict__ Wt,
    const float* __restrict__ bias, float bscale, u16* __restrict__ outp)
{
    proj_body<true>(A, nullptr, Wt, bias, bscale, outp, blockIdx.y * 128, blockIdx.x * 128);
}

// final combined proj: 288 linear blocks (128 x_out [dual-A], 128 i_x_out, 32 k_out)
__global__ __launch_bounds__(256, 3) void gemm_proj3_k(
    const u16* __restrict__ A0, const u16* __restrict__ A0b,
    const u16* __restrict__ A1, const u16* __restrict__ A2,
    const u16* __restrict__ W, const u16* __restrict__ Wi2,
    const float* __restrict__ bp, const float* __restrict__ bpi2,
    float* __restrict__ o0, float* __restrict__ o1, float* __restrict__ o2)
{
    const int id = blockIdx.x;
    const u16 *A, *Ax; const u16* Wt; const float* bias; float bscale; float* outp; int x, y;
    if (id < 128)      { A = A0; Ax = A0b; Wt = W;   bias = bp;   bscale = 2.0f; outp = o0; x = id & 3; y = id >> 2; }
    else if (id < 256) { A = A1; Ax = nullptr; Wt = Wi2; bias = bpi2; bscale = 1.0f; outp = o1; x = (id - 128) & 3; y = (id - 128) >> 2; }
    else               { A = A2; Ax = nullptr; Wt = W;   bias = bp;   bscale = 1.0f; outp = o2; x = (id - 256) & 3; y = (id - 256) >> 2; }
    proj_body<false>(A, Ax, Wt, bias, bscale, outp, y * 128, x * 128);
}

// ---------------------------------------------------------------------------
// Paired wide scores with coalesced S epilogue via LDS restage.
// z<32 -> (KQ,KX)->SPa ; else (IKQ,IK)->SPb. R=256,C=1024.
// ---------------------------------------------------------------------------
__global__ __launch_bounds__(256, 4) void scores_pair_k(
    const u16* __restrict__ A1, const u16* __restrict__ B1, u16* __restrict__ S1,
    const u16* __restrict__ A2, const u16* __restrict__ B2, u16* __restrict__ S2)
{
    __shared__ __align__(16) short Ls[2 * 128 * 72];
    short* As = Ls;
    short* Bs = Ls + 128 * 72;
    const int z = blockIdx.z, bh = z & 31;
    const u16* Aq = (z < 32) ? A1 : A2;
    const u16* Bk = (z < 32) ? B1 : B2;
    u16* S = (z < 32) ? S1 : S2;
    const int tid = threadIdx.x;
    const int wave = tid >> 6, lane = tid & 63;
    const int lr = lane & 15, lg = lane >> 4, lk = lg * 8;
    const int rb = blockIdx.y * 128, cb = blockIdx.x * 128;
    const int wr = (wave >> 1) * 64, wc = (wave & 1) * 64;
    const u16* Ap = Aq + (size_t)bh * 256 * 64;
    const u16* Bp = Bk + (size_t)bh * 1024 * 64;
    const int srow = tid >> 3, skc = (tid & 7) * 8;
    #pragma unroll
    for (int it = 0; it < 4; ++it) {
        int row = it * 32 + srow;
        *reinterpret_cast<bf16x8*>(&As[row * 72 + skc]) =
            *reinterpret_cast<const bf16x8*>(Ap + (size_t)(rb + row) * 64 + skc);
        *reinterpret_cast<bf16x8*>(&Bs[row * 72 + skc]) =
            *reinterpret_cast<const bf16x8*>(Bp + (size_t)(cb + row) * 64 + skc);
    }
    __syncthreads();
    f32x4 acc[4][4] = {};
    #pragma unroll
    for (int ks = 0; ks < 2; ++ks) {
        bf16x8 af[4], bf_[4];
        #pragma unroll
        for (int mi = 0; mi < 4; ++mi)
            af[mi] = *reinterpret_cast<const bf16x8*>(&As[(wr + mi * 16 + lr) * 72 + ks * 32 + lk]);
        #pragma unroll
        for (int ni = 0; ni < 4; ++ni)
            bf_[ni] = *reinterpret_cast<const bf16x8*>(&Bs[(wc + ni * 16 + lr) * 72 + ks * 32 + lk]);
        #pragma unroll
        for (int mi = 0; mi < 4; ++mi)
            #pragma unroll
            for (int ni = 0; ni < 4; ++ni)
                acc[mi][ni] = mfma16(af[mi], bf_[ni], acc[mi][ni]);
    }
    __syncthreads();   // all LDS reads done -> reuse Ls as [128][136] epilogue buffer
    #pragma unroll
    for (int mi = 0; mi < 4; ++mi)
        #pragma unroll
        for (int ni = 0; ni < 4; ++ni) {
            int row = wr + mi * 16 + lg * 4;
            int col = wc + ni * 16 + lr;
            f32x4 v = acc[mi][ni];
            #pragma unroll
            for (int j = 0; j < 4; ++j)
                Ls[(row + j) * 136 + col] = (short)f2b(v[j]);
        }
    __syncthreads();
    #pragma unroll
    for (int p = 0; p < 8; ++p) {
        int slot = p * 256 + tid;
        int row = slot >> 4;
        int chunk = slot & 15;
        u16x8 val = *reinterpret_cast<u16x8*>(&Ls[row * 136 + chunk * 8]);
        *reinterpret_cast<u16x8*>(
            &S[((size_t)bh * 256 + rb + row) * 1024 + cb + chunk * 8]) = val;
    }
}

// ---------------------------------------------------------------------------
// Paired wide softmax: rows [0,8192) -> SPa + bf16 bias1 ; [8192,16384) ->
// SPb + u8 maskT (-1e9).
// ---------------------------------------------------------------------------
__global__ __launch_bounds__(256) void softmax_pair_k(
    u16* __restrict__ S1, const u16* __restrict__ bias1,
    u16* __restrict__ S2, const unsigned char* __restrict__ maskT)
{
    const int rg = blockIdx.x;
    const bool first = rg < 8192;
    const int row_g = first ? rg : rg - 8192;
    const int tid = threadIdx.x;
    const int wave = tid >> 6, lane = tid & 63;
    const int c = tid * 4;
    u16* rowp = (first ? S1 : S2) + (size_t)row_g * 1024;
    ushort4 sv = *reinterpret_cast<const ushort4*>(rowp + c);
    float s[4] = { b2f(sv.x), b2f(sv.y), b2f(sv.z), b2f(sv.w) };
    if (first) {
        ushort4 bv = *reinterpret_cast<const ushort4*>(bias1 + (size_t)row_g * 1024 + c);
        s[0] += b2f(bv.x); s[1] += b2f(bv.y); s[2] += b2f(bv.z); s[3] += b2f(bv.w);
    } else {
        uchar4 mk = *reinterpret_cast<const uchar4*>(maskT + (size_t)row_g * 1024 + c);
        if (mk.x) s[0] = -1e9f; if (mk.y) s[1] = -1e9f;
        if (mk.z) s[2] = -1e9f; if (mk.w) s[3] = -1e9f;
    }
    __shared__ float swv[4];
    float lm = fmaxf(fmaxf(s[0], s[1]), fmaxf(s[2], s[3]));
    lm = wred_max(lm);
    if (lane == 0) swv[wave] = lm;
    __syncthreads();
    float m = fmaxf(fmaxf(swv[0], swv[1]), fmaxf(swv[2], swv[3]));
    __syncthreads();
    float ls = 0.0f;
    #pragma unroll
    for (int j = 0; j < 4; ++j) { s[j] = __expf(s[j] - m); ls += s[j]; }
    ls = wred_sum(ls);
    if (lane == 0) swv[wave] = ls;
    __syncthreads();
    float inv = 1.0f / (swv[0] + swv[1] + swv[2] + swv[3]);
    ushort4 ov = { f2b(s[0] * inv), f2b(s[1] * inv), f2b(s[2] * inv), f2b(s[3] * inv) };
    *reinterpret_cast<ushort4*>(rowp + c) = ov;
}

// ---------------------------------------------------------------------------
// Paired PV with coalesced per-wave epilogue. z=0: (SPa,VXt)->KMb ;
// z=1: (SPb,IVt)->KMb2
// ---------------------------------------------------------------------------
__global__ __launch_bounds__(256, 4) void pv_pair_k(
    const u16* __restrict__ P1, const u16* __restrict__ V1, u16* __restrict__ o1,
    const u16* __restrict__ P2, const u16* __restrict__ V2, u16* __restrict__ o2)
{
    __shared__ __align__(16) short Ps[4 * 16 * 72];
    const int z = blockIdx.z;
    const u16* P = z ? P2 : P1;
    const u16* V = z ? V2 : V1;
    u16* out = z ? o2 : o1;
    const int tid = threadIdx.x;
    const int wave = tid >> 6, lane = tid & 63;
    const int lr = lane & 15, lg = lane >> 4, lk = lg * 8;
    const int bh = blockIdx.y, b = bh >> 3, h = bh & 7;
    const int rb = blockIdx.x * 64;
    const int wr = wave * 16;
    f32x4 acc[4] = {};
    const u16* Pb = P + ((size_t)bh * 256 + rb) * 1024;
    const u16* Vb = V + (size_t)bh * 64 * 1024;
    for (int c0 = 0; c0 < 1024; c0 += 64) {
        #pragma unroll
        for (int ks = 0; ks < 2; ++ks) {
            bf16x8 ap = *reinterpret_cast<const bf16x8*>(
                Pb + (size_t)(wr + lr) * 1024 + c0 + ks * 32 + lk);
            #pragma unroll
            for (int ni = 0; ni < 4; ++ni) {
                bf16x8 vv = *reinterpret_cast<const bf16x8*>(
                    Vb + (size_t)(ni * 16 + lr) * 1024 + c0 + ks * 32 + lk);
                acc[ni] = mfma16(ap, vv, acc[ni]);
            }
        }
    }
    short* myP = &Ps[wave * 16 * 72];
    #pragma unroll
    for (int ni = 0; ni < 4; ++ni) {
        int d = ni * 16 + lr;
        f32x4 v = acc[ni];
        #pragma unroll
        for (int j = 0; j < 4; ++j)
            myP[(lg * 4 + j) * 72 + d] = (short)f2b(v[j]);
    }
    #pragma unroll
    for (int p = 0; p < 2; ++p) {
        int slot = p * 64 + lane;
        int rloc = slot >> 3;
        int inner = slot & 7;
        int r0 = rb + wr + rloc;
        u16x8 val = *reinterpret_cast<u16x8*>(&myP[rloc * 72 + inner * 8]);
        *reinterpret_cast<u16x8*>(
            &out[((size_t)(b * 256 + r0)) * 512 + h * 64 + inner * 8]) = val;
    }
}

// ---------------------------------------------------------------------------
// Merged fused attention: 1536 blocks.
//  [0,512)    : branch2 src0 (Q, KK, KVt, biasF bf16)  -> XMb
//  [512,1024) : branch2 src1 (Q, IKK, IKVt, crossB8 u8)-> XMc
//  [1024,1536): branch3     (IQ, K2K, K2Vt, iattB8 u8) -> XMb2
// 64 x-rows/block, 4 waves, wave owns 16 rows, zero barriers.
// ---------------------------------------------------------------------------
__global__ __launch_bounds__(256, 4) void attn_all_k(
    const u16* __restrict__ Q0, const u16* __restrict__ IQ0,
    const u16* __restrict__ K1, const u16* __restrict__ V1t,
    const u16* __restrict__ B1F, u16* __restrict__ out1,
    const u16* __restrict__ K2, const u16* __restrict__ V2t,
    const unsigned char* __restrict__ B2M, u16* __restrict__ out2,
    const u16* __restrict__ K3, const u16* __restrict__ V3t,
    const unsigned char* __restrict__ B3M, u16* __restrict__ out3)
{
    const int tid = threadIdx.x;
    const int w = tid >> 6, lane = tid & 63;
    const int lr = lane & 15, lg = lane >> 4, lk = lg * 8;
    int lin = blockIdx.x;
    const u16 *Qp, *Kp, *Vp; const u16* BF = nullptr;
    const unsigned char* BM = nullptr; u16* outm;
    if (lin < 512)        { Qp = Q0;  Kp = K1; Vp = V1t; BF = B1F; outm = out1; }
    else if (lin < 1024)  { Qp = Q0;  Kp = K2; Vp = V2t; BM = B2M; outm = out2; lin -= 512; }
    else                  { Qp = IQ0; Kp = K3; Vp = V3t; BM = B3M; outm = out3; lin -= 1024; }
    const int xcd = lin & 7, idx = lin >> 3;
    const int bh = xcd * 4 + (idx & 3);
    const int rb = (idx >> 2) * 64;
    const int b = bh >> 3, h = bh & 7;
    const int wr = w * 16;
    const int strip = (rb >> 4) + w;

    __shared__ __align__(16) short Ps[4 * 16 * 264];   // per-wave scratch
    short* myP = &Ps[w * 16 * 264];

    bf16x8 qf0, qf1;
    {
        const u16* Qb = Qp + ((size_t)bh * 1024 + rb + wr + lr) * 64;
        qf0 = *reinterpret_cast<const bf16x8*>(Qb + lk);
        qf1 = *reinterpret_cast<const bf16x8*>(Qb + 32 + lk);
    }

    // bias prefetch: bf16 (seg0) = 8x16B loads; u8 mask (seg1/2) = 8x8B loads
    bf16x8 breg[8];
    u64 mreg[8];
    if (BF) {
        const u16* bb = BF + (((size_t)bh * 64 + strip) * 8) * 512 + (size_t)lane * 8;
        #pragma unroll
        for (int itp = 0; itp < 8; ++itp)
            breg[itp] = *reinterpret_cast<const bf16x8*>(bb + (size_t)itp * 512);
    } else {
        const unsigned char* bb = BM + (((size_t)bh * 64 + strip) * 8) * 512 + (size_t)lane * 8;
        #pragma unroll
        for (int itp = 0; itp < 8; ++itp)
            mreg[itp] = *reinterpret_cast<const u64*>(bb + (size_t)itp * 512);
    }
    // scores: 16 rows x 256 cols per wave; K direct from global (L2)
    const u16* Kb = Kp + (size_t)bh * 256 * 64;
    f32x4 acc[16];
    #pragma unroll
    for (int ni = 0; ni < 16; ++ni) acc[ni] = (f32x4){0.f, 0.f, 0.f, 0.f};
    #pragma unroll
    for (int ni = 0; ni < 16; ++ni) {
        bf16x8 b0 = *reinterpret_cast<const bf16x8*>(Kb + (size_t)(ni * 16 + lr) * 64 + lk);
        acc[ni] = mfma16(qf0, b0, acc[ni]);
    }
    #pragma unroll
    for (int ni = 0; ni < 16; ++ni) {
        bf16x8 b1 = *reinterpret_cast<const bf16x8*>(Kb + (size_t)(ni * 16 + lr) * 64 + 32 + lk);
        acc[ni] = mfma16(qf1, b1, acc[ni]);
    }
    // bias from regs + in-wave softmax
    float mx[4] = { -3.4e38f, -3.4e38f, -3.4e38f, -3.4e38f };
    if (BF) {
        #pragma unroll
        for (int ni = 0; ni < 16; ++ni) {
            const bf16x8 br = breg[ni >> 1];
            #pragma unroll
            for (int j = 0; j < 4; ++j) {
                float v = acc[ni][j] + b2f((u16)br[(ni & 1) * 4 + j]);
                acc[ni][j] = v;
                mx[j] = fmaxf(mx[j], v);
            }
        }
    } else {
        #pragma unroll
        for (int ni = 0; ni < 16; ++ni) {
            const u64 mm = mreg[ni >> 1];
            #pragma unroll
            for (int j = 0; j < 4; ++j) {
                float v = acc[ni][j];
                if ((mm >> (((ni & 1) * 4 + j) * 8)) & 0xFF) v = -1e9f;
                acc[ni][j] = v;
                mx[j] = fmaxf(mx[j], v);
            }
        }
    }
    #pragma unroll
    for (int j = 0; j < 4; ++j) {
        #pragma unroll
        for (int o = 1; o < 16; o <<= 1) mx[j] = fmaxf(mx[j], __shfl_xor(mx[j], o, 64));
    }
    float sm[4] = {};
    #pragma unroll
    for (int ni = 0; ni < 16; ++ni) {
        #pragma unroll
        for (int j = 0; j < 4; ++j) {
            float e = __expf(acc[ni][j] - mx[j]);
            acc[ni][j] = e;
            sm[j] += e;
        }
    }
    #pragma unroll
    for (int j = 0; j < 4; ++j) {
        #pragma unroll
        for (int o = 1; o < 16; o <<= 1) sm[j] += __shfl_xor(sm[j], o, 64);
        sm[j] = 1.0f / sm[j];
    }
    // P to wave-local LDS (in-wave transpose), then PV with V from global
    #pragma unroll
    for (int ni = 0; ni < 16; ++ni)
        #pragma unroll
        for (int j = 0; j < 4; ++j)
            myP[(lg * 4 + j) * 264 + ni * 16 + lr] = (short)f2b(acc[ni][j] * sm[j]);
    f32x4 acc2[4] = {};
    #pragma unroll
    for (int kc = 0; kc < 8; ++kc) {
        bf16x8 ap = *reinterpret_cast<const bf16x8*>(&myP[lr * 264 + kc * 32 + lk]);
        #pragma unroll
        for (int ni = 0; ni < 4; ++ni) {
            bf16x8 vv = *reinterpret_cast<const bf16x8*>(
                Vp + ((size_t)bh * 64 + ni * 16 + lr) * 256 + kc * 32 + lk);
            acc2[ni] = mfma16(ap, vv, acc2[ni]);
        }
    }
    // coalesced epilogue: restage 16x64 tile (stride 72), 8 lanes per 128B row
    #pragma unroll
    for (int ni = 0; ni < 4; ++ni) {
        int d = ni * 16 + lr;
        f32x4 v = acc2[ni];
        #pragma unroll
        for (int j = 0; j < 4; ++j)
            myP[(lg * 4 + j) * 72 + d] = (short)f2b(v[j]);
    }
    #pragma unroll
    for (int p = 0; p < 2; ++p) {
        int slot = p * 64 + lane;
        int rloc = slot >> 3;
        int inner = slot & 7;
        int row = rb + wr + rloc;
        u16x8 val = *reinterpret_cast<u16x8*>(&myP[rloc * 72 + inner * 8]);
        *reinterpret_cast<u16x8*>(
            &outm[((size_t)(b * 1024 + row)) * 512 + h * 64 + inner * 8]) = val;
    }
}

// ---------------------------------------------------------------------------
extern "C" void kernel_launch(void* const* d_in, const int* in_sizes, int n_in,
                              void* d_out, int out_size, void* d_ws, size_t ws_size,
                              hipStream_t stream)
{
    const float* x        = (const float*)d_in[0];
    const float* kernal   = (const float*)d_in[1];
    const float* i_x      = (const float*)d_in[2];
    const float* i_kernal = (const float*)d_in[3];
    const int*   rd       = (const int*)d_in[4];
    const int*   polar    = (const int*)d_in[5];
    const int*   att      = (const int*)d_in[6];
    const int*   i_att    = (const int*)d_in[7];
    const int*   cross    = (const int*)d_in[8];
    const float* Wqkv     = (const float*)d_in[9];
    const float* Wqkv_i   = (const float*)d_in[10];
    const float* Wqkv_i2  = (const float*)d_in[11];
    const float* Wproj    = (const float*)d_in[12];
    const float* bproj    = (const float*)d_in[13];
    const float* Wproj_i  = (const float*)d_in[14];
    const float* bproj_i  = (const float*)d_in[15];
    const float* Wproj_i2 = (const float*)d_in[16];
    const float* bproj_i2 = (const float*)d_in[17];
    const float* dis      = (const float*)d_in[18];
    const float* pemb     = (const float*)d_in[19];

    float* out = (float*)d_out;
    float* x_out   = out;
    float* k_out   = out + (size_t)BB * XLL * DIMM;
    float* i_x_out = k_out + (size_t)BB * KLL * DIMM;

    char* ws = (char*)d_ws;
    size_t off = 0;
    auto alloc = [&](size_t bytes) { void* p = ws + off; off += (bytes + 255) & ~(size_t)255; return p; };

    const size_t NAX = (size_t)BB * XLL * DIMM;
    const size_t NAK = (size_t)BB * KLL * DIMM;
    const size_t NHX = (size_t)BHH * XLL * HEADD;
    const size_t NHK = (size_t)BHH * KLL * HEADD;
    const size_t NS  = (size_t)BHH * KLL * XLL;

    u16* WqkvT    = (u16*)alloc((size_t)1536 * 512 * 2);
    u16* WqkvIT   = (u16*)alloc((size_t)1536 * 512 * 2);
    u16* WqkvI2T  = (u16*)alloc((size_t)1536 * 512 * 2);
    u16* WprojT   = (u16*)alloc((size_t)512 * 512 * 2);
    u16* WprojIT  = (u16*)alloc((size_t)512 * 512 * 2);
    u16* WprojI2T = (u16*)alloc((size_t)512 * 512 * 2);
    u16* Q    = (u16*)alloc(NHX * 2);
    u16* KX   = (u16*)alloc(NHX * 2);
    u16* VXt  = (u16*)alloc(NHX * 2);
    u16* IQ   = (u16*)alloc(NHX * 2);
    u16* IK   = (u16*)alloc(NHX * 2);
    u16* IVt  = (u16*)alloc(NHX * 2);
    u16* KQ   = (u16*)alloc(NHK * 2);
    u16* KK   = (u16*)alloc(NHK * 2);
    u16* KVt  = (u16*)alloc(NHK * 2);
    u16* IKQ  = (u16*)alloc(NHK * 2);
    u16* IKK  = (u16*)alloc(NHK * 2);
    u16* IKVt = (u16*)alloc(NHK * 2);
    u16* K2K  = (u16*)alloc(NHK * 2);
    u16* K2Vt = (u16*)alloc(NHK * 2);
    u16* SPa  = (u16*)alloc(NS * 2);
    u16* SPb  = (u16*)alloc(NS * 2);
    u16* KMb  = (u16*)alloc(NAK * 2);
    u16* KMb2 = (u16*)alloc(NAK * 2);
    u16* XMb  = (u16*)alloc(NAX * 2);
    u16* XMb2 = (u16*)alloc(NAX * 2);
    u16* XMc  = (u16*)alloc(NAX * 2);
    u16* IKOUTb = (u16*)alloc(NAK * 2);
    u16* biasF = (u16*)alloc(NS * 2);
    u16* bias1 = (u16*)alloc(NS * 2);
    unsigned char* crossB8 = (unsigned char*)alloc(NS);
    unsigned char* iattB8  = (unsigned char*)alloc(NS);
    unsigned char* iattT8  = (unsigned char*)alloc(NS);
    int* MO   = (int*)alloc((size_t)BHH * KLL * 4);

    dim3 blk(256);

    // 1. merged prep (weight transposes + mask conversions, u8 frag masks)
    prep_all_k<<<dim3(19456), blk, 0, stream>>>(
        Wqkv, Wqkv_i, Wqkv_i2, Wproj, Wproj_i, Wproj_i2,
        WqkvT, WqkvIT, WqkvI2T, WprojT, WprojIT, WprojI2T,
        i_att, iattT8, iattB8, cross, crossB8);

    // 2. all first-stage QKV GEMMs (cast fused, q pre-scaled), XCD-swizzled
    gemm_qkv_all_k<<<dim3(960), blk, 0, stream>>>(
        x, kernal, i_x, i_kernal, WqkvT, WqkvIT,
        Q, KX, VXt, KQ, KK, KVt, IQ, IK, IVt, IKQ, IKK, IKVt);

    // 3. wide scores (branch1 + branch3)
    scores_pair_k<<<dim3(8, 2, 64), blk, 0, stream>>>(KQ, KX, SPa, IKQ, IK, SPb);
    // 4. main orientation + bias builds
    main_ori_k8<<<dim3(BB * KLL), blk, 0, stream>>>(SPa, polar, MO);
    bias_build_k<<<dim3(32, 8, BB), blk, 0, stream>>>(rd, polar, att, dis, pemb, MO, biasF, bias1);
    // 5. wide softmaxes
    softmax_pair_k<<<dim3(16384), blk, 0, stream>>>(SPa, bias1, SPb, iattT8);
    // 6. wide PVs (barrier-free)
    pv_pair_k<<<dim3(4, 32, 2), blk, 0, stream>>>(SPa, VXt, KMb, SPb, IVt, KMb2);
    // 7. IKOUT proj (bf16) + second qkv (k/v columns only)
    gemm_proj_bf16_k<<<dim3(4, 8), blk, 0, stream>>>(KMb2, WprojIT, bproj_i, 1.0f, IKOUTb);
    gemm_qkv2_k<<<dim3(8, 8), blk, 0, stream>>>(IKOUTb, WqkvI2T, K2K, K2Vt);
    // 8. all three fused attentions in one launch (1536 blocks)
    attn_all_k<<<dim3(1536), blk, 0, stream>>>(
        Q, IQ, KK, KVt, biasF, XMb, IKK, IKVt, crossB8, XMc,
        K2K, K2Vt, iattB8, XMb2);
    // 9. final combined projections (x_out = (XMb+XMc)@W, i_x_out, k_out)
    gemm_proj3_k<<<dim3(288), blk, 0, stream>>>(
        XMb, XMc, XMb2, KMb, WprojT, WprojI2T, bproj, bproj_i2, x_out, i_x_out, k_out);

    (void)in_sizes; (void)n_in; (void)out_size; (void)ws_size;
}

// Round 19
// 260.832 us; speedup vs baseline: 1.1128x; 1.1128x over previous
//
#include <hip/hip_runtime.h>
#include <cstddef>
#include <cstdint>

#define BB 4
#define HH 8
#define HEADD 64
#define DIMM 512
#define XLL 1024
#define KLL 256
#define BHH (BB*HH)

typedef __attribute__((ext_vector_type(8))) short bf16x8;
typedef __attribute__((ext_vector_type(8))) unsigned short u16x8;
typedef __attribute__((ext_vector_type(4))) float f32x4;
typedef unsigned short u16;
typedef unsigned long long u64;

__device__ __forceinline__ u16 f2b(float f) {
    unsigned int u = __builtin_bit_cast(unsigned int, f);
    u = u + 0x7fffu + ((u >> 16) & 1u);
    return (u16)(u >> 16);
}
__device__ __forceinline__ float b2f(u16 h) {
    unsigned int u = ((unsigned int)h) << 16;
    return __builtin_bit_cast(float, u);
}
__device__ __forceinline__ f32x4 mfma16(bf16x8 a, bf16x8 b, f32x4 c) {
    return __builtin_amdgcn_mfma_f32_16x16x32_bf16(a, b, c, 0, 0, 0);
}
__device__ __forceinline__ float wred_max(float v) {
    #pragma unroll
    for (int o = 1; o < 64; o <<= 1) v = fmaxf(v, __shfl_xor(v, o, 64));
    return v;
}
__device__ __forceinline__ float wred_sum(float v) {
    #pragma unroll
    for (int o = 1; o < 64; o <<= 1) v += __shfl_xor(v, o, 64);
    return v;
}

// Fragment-order layout (element == byte index for u8 variant):
//   E(bh,x,k) = ((bh*64 + (x>>4))*8 + (k>>5))*512
//             + (((x>>2)&3)*16 + (k&15))*8 + ((k>>4)&1)*4 + (x&3)

// ---------------------------------------------------------------------------
// Merged prep: blocks [0,3072) = 6 weight transposes (f32 [K][N]->bf16 [N][K]);
// blocks [3072,19456): mask prep. z<32: i_att -> iattT8 (u8 [bh,k,x]) +
// iattB8 (u8 fragment order). z>=32: cross -> crossB8 (u8 fragment order).
// ---------------------------------------------------------------------------
__global__ __launch_bounds__(256) void prep_all_k(
    const float* __restrict__ s0, const float* __restrict__ s1,
    const float* __restrict__ s2, const float* __restrict__ s3,
    const float* __restrict__ s4, const float* __restrict__ s5,
    u16* __restrict__ d0, u16* __restrict__ d1, u16* __restrict__ d2,
    u16* __restrict__ d3, u16* __restrict__ d4, u16* __restrict__ d5,
    const int* __restrict__ i_att, unsigned char* __restrict__ iattT8,
    unsigned char* __restrict__ iattB8,
    const int* __restrict__ cross, unsigned char* __restrict__ crossB8)
{
    const int id = blockIdx.x;
    if (id < 3072) {
        __shared__ float t[32][33];
        const float* W; u16* Wt; int N, bx, by;
        if (id < 2304) {
            int which = id / 768, local = id - which * 768;
            W = which == 0 ? s0 : (which == 1 ? s1 : s2);
            Wt = which == 0 ? d0 : (which == 1 ? d1 : d2);
            N = 1536; bx = local % 48; by = local / 48;
        } else {
            int which = (id - 2304) / 256, local = (id - 2304) % 256;
            W = which == 0 ? s3 : (which == 1 ? s4 : s5);
            Wt = which == 0 ? d3 : (which == 1 ? d4 : d5);
            N = 512; bx = local % 16; by = local / 16;
        }
        const int K = 512;
        int tx = threadIdx.x & 31, ty = threadIdx.x >> 5;
        #pragma unroll
        for (int r = ty; r < 32; r += 8)
            t[r][tx] = W[(size_t)(by * 32 + r) * N + bx * 32 + tx];
        __syncthreads();
        #pragma unroll
        for (int r = ty; r < 32; r += 8)
            Wt[(size_t)(bx * 32 + r) * K + by * 32 + tx] = f2b(t[tx][r]);
        return;
    }
    const int id2 = id - 3072;
    const int xt = id2 & 31, kt = (id2 >> 5) & 7, z = id2 >> 8;
    const int bh = z & 31;
    const int tid = threadIdx.x;
    const int sl = tid >> 7, rem = tid & 127, l = rem >> 1, nilow = rem & 1;
    const int lg = l >> 4, lr_ = l & 15;
    const int xl0 = sl * 16 + lg * 4, kl = nilow * 16 + lr_;
    if (z < 32) {
        __shared__ unsigned char t8[32][33];   // [x][k]
        const int tx = tid & 31, ty = tid >> 5;
        #pragma unroll
        for (int r = ty; r < 32; r += 8)
            t8[r][tx] = (unsigned char)(i_att[((size_t)bh * 1024 + xt * 32 + r) * 256 + kt * 32 + tx] != 0);
        __syncthreads();
        #pragma unroll
        for (int r = ty; r < 32; r += 8)
            iattT8[((size_t)bh * 256 + kt * 32 + r) * 1024 + xt * 32 + tx] = t8[tx][r];
        uchar4 o;
        o.x = t8[xl0 + 0][kl]; o.y = t8[xl0 + 1][kl];
        o.z = t8[xl0 + 2][kl]; o.w = t8[xl0 + 3][kl];
        size_t eb = (((size_t)bh * 64 + xt * 2 + sl) * 8 + kt) * 512 + (size_t)l * 8 + nilow * 4;
        *reinterpret_cast<uchar4*>(iattB8 + eb) = o;
    } else {
        const int kg = kt * 32 + kl;
        uchar4 o;
        o.x = (unsigned char)(cross[((size_t)bh * 1024 + xt * 32 + xl0 + 0) * 256 + kg] != 0);
        o.y = (unsigned char)(cross[((size_t)bh * 1024 + xt * 32 + xl0 + 1) * 256 + kg] != 0);
        o.z = (unsigned char)(cross[((size_t)bh * 1024 + xt * 32 + xl0 + 2) * 256 + kg] != 0);
        o.w = (unsigned char)(cross[((size_t)bh * 1024 + xt * 32 + xl0 + 3) * 256 + kg] != 0);
        size_t eb = (((size_t)bh * 64 + xt * 2 + sl) * 8 + kt) * 512 + (size_t)l * 8 + nilow * 4;
        *reinterpret_cast<uchar4*>(crossB8 + eb) = o;
    }
}

// ---------------------------------------------------------------------------
// main orientation: block per (b,k); reads polar row once, loops 8 heads.
// ---------------------------------------------------------------------------
__global__ __launch_bounds__(256) void main_ori_k8(
    const u16* __restrict__ S, const int* __restrict__ polar,
    int* __restrict__ MO)
{
    const int blk = blockIdx.x;          // b*256 + k
    const int b = blk >> 8, k = blk & 255;
    const int tid = threadIdx.x;
    const int wave = tid >> 6, lane = tid & 63;
    const int c = tid * 4;
    int4 p4 = *reinterpret_cast<const int4*>(polar + ((size_t)b * 256 + k) * 1024 + c);
    int pp[4] = { p4.x, p4.y, p4.z, p4.w };
    #pragma unroll
    for (int j = 0; j < 4; ++j) { int p = pp[j]; pp[j] = p < 0 ? 0 : (p > 7 ? 7 : p); }
    __shared__ float sred[4][8];
    for (int h = 0; h < 8; ++h) {
        const int bh = b * 8 + h;
        ushort4 sv = *reinterpret_cast<const ushort4*>(S + ((size_t)bh * 256 + k) * 1024 + c);
        float av[4] = { fabsf(b2f(sv.x)), fabsf(b2f(sv.y)), fabsf(b2f(sv.z)), fabsf(b2f(sv.w)) };
        float bins[8] = {};
        #pragma unroll
        for (int j = 0; j < 4; ++j) {
            #pragma unroll
            for (int o = 0; o < 8; ++o) bins[o] += (pp[j] == o) ? av[j] : 0.0f;
        }
        #pragma unroll
        for (int o = 0; o < 8; ++o) bins[o] = wred_sum(bins[o]);
        if (lane == 0) {
            #pragma unroll
            for (int o = 0; o < 8; ++o) sred[wave][o] = bins[o];
        }
        __syncthreads();
        if (tid == 0) {
            int best = 0; float bv = -1.0f;
            #pragma unroll
            for (int o = 0; o < 8; ++o) {
                float s = sred[0][o] + sred[1][o] + sred[2][o] + sred[3][o];
                if (s > bv) { bv = s; best = o; }
            }
            MO[bh * 256 + k] = best;
        }
        __syncthreads();
    }
}

// ---------------------------------------------------------------------------
// Combined bias build (after MO): biasF fragment order (-1e9) + bias1 [bh,k,x] (-1e6)
// ---------------------------------------------------------------------------
__global__ __launch_bounds__(256) void bias_build_k(
    const int* __restrict__ rd, const int* __restrict__ polar,
    const int* __restrict__ att, const float* __restrict__ dis,
    const float* __restrict__ pemb, const int* __restrict__ MO,
    u16* __restrict__ biasF, u16* __restrict__ bias1)
{
    const int b = blockIdx.z;
    const int xt = blockIdx.x * 32, kt = blockIdx.y * 32;
    const int tid = threadIdx.x;
    __shared__ float dsh[528];
    __shared__ int rds[32][33];   // [x][k]
    __shared__ int pls[32][33];
    __shared__ u16 bt[32][33];    // -1e6 variant [x][k]
    for (int i = tid; i < 528; i += 256) dsh[i] = dis[i];
    const int tx = tid & 31, ty = tid >> 5;
    #pragma unroll
    for (int r = ty; r < 32; r += 8) {
        size_t src = ((size_t)b * 256 + kt + r) * 1024 + xt + tx;  // rd[b,k,x]
        rds[tx][r] = rd[src];
        int p = polar[src]; pls[tx][r] = p < 0 ? 0 : (p > 7 ? 7 : p);
    }
    float pe[8];
    #pragma unroll
    for (int o = 0; o < 8; ++o) pe[o] = pemb[o];
    __syncthreads();
    const int sl = tid >> 7, rem = tid & 127, l = rem >> 1, nilow = rem & 1;
    const int lg = l >> 4, lr_ = l & 15;
    const int xl0 = sl * 16 + lg * 4, kl = nilow * 16 + lr_;
    const int kg = kt + kl;
    const u16 NEG9 = f2b(-1e9f), NEG6 = f2b(-1e6f);
    for (int h = 0; h < 8; ++h) {
        const int bh = b * 8 + h;
        int mo = MO[bh * 256 + kg];
        u16 o9[4];
        #pragma unroll
        for (int j = 0; j < 4; ++j) {
            int xl = xl0 + j;
            int mm = att[((size_t)bh * 1024 + xt + xl) * 256 + kg];
            float v = dsh[rds[xl][kl] * 8 + h] + pe[(pls[xl][kl] - mo + 8) & 7];
            u16 vb = f2b(v);
            o9[j] = mm ? NEG9 : vb;
            bt[xl][kl] = mm ? NEG6 : vb;
        }
        size_t eb = (((size_t)bh * 64 + (xt >> 4) + sl) * 8 + (kt >> 5)) * 512 + (size_t)l * 8 + nilow * 4;
        ushort4 ov; ov.x = o9[0]; ov.y = o9[1]; ov.z = o9[2]; ov.w = o9[3];
        *reinterpret_cast<ushort4*>(biasF + eb) = ov;
        __syncthreads();
        const int k_ = tid >> 3, x4 = (tid & 7) * 4;
        ushort4 o2;
        o2.x = bt[x4 + 0][k_]; o2.y = bt[x4 + 1][k_];
        o2.z = bt[x4 + 2][k_]; o2.w = bt[x4 + 3][k_];
        *reinterpret_cast<ushort4*>(bias1 + ((size_t)bh * 256 + kt + k_) * 1024 + xt + x4) = o2;
        __syncthreads();
    }
}

// ---------------------------------------------------------------------------
// Software-pipelined 128x128 staged MFMA core. AT = float (cast fused at
// staging) or u16. Optional A2 (bf16): summed into A at staging (runtime).
// ---------------------------------------------------------------------------
template<typename AT>
__device__ __forceinline__ void gemm_core_128(
    const AT* __restrict__ A, const AT* __restrict__ A2,
    const u16* __restrict__ Wt,
    int rb, int cb, short* Asl, short* Bsl, f32x4 (&acc)[4][4])
{
    constexpr bool F32 = sizeof(AT) == 4;
    const int tid = threadIdx.x;
    const int w = tid >> 6, lane = tid & 63;
    const int lr = lane & 15, lk = (lane >> 4) * 8;
    const int wr = (w >> 1) * 64, wc = (w & 1) * 64;
    const int srow = tid >> 3, skc = (tid & 7) * 8;
    const AT* gA = A + (size_t)(rb + srow) * 512 + skc;
    const AT* gA2 = A2 ? A2 + (size_t)(rb + srow) * 512 + skc : nullptr;
    const u16* gB = Wt + (size_t)(cb + srow) * 512 + skc;
    float4 ral[4], rah[4];
    bf16x8 rab[4], rab2[4], rw[4];
    #pragma unroll
    for (int it = 0; it < 4; ++it) {
        if constexpr (F32) {
            ral[it] = *reinterpret_cast<const float4*>(gA + (size_t)it * 32 * 512);
            rah[it] = *reinterpret_cast<const float4*>(gA + (size_t)it * 32 * 512 + 4);
        } else {
            rab[it] = *reinterpret_cast<const bf16x8*>(gA + (size_t)it * 32 * 512);
            if (gA2) rab2[it] = *reinterpret_cast<const bf16x8*>(gA2 + (size_t)it * 32 * 512);
        }
        rw[it] = *reinterpret_cast<const bf16x8*>(gB + (size_t)it * 32 * 512);
    }
    for (int t = 0; t < 8; ++t) {
        #pragma unroll
        for (int it = 0; it < 4; ++it) {
            if constexpr (F32) {
                u16x8 o;
                o[0] = f2b(ral[it].x); o[1] = f2b(ral[it].y);
                o[2] = f2b(ral[it].z); o[3] = f2b(ral[it].w);
                o[4] = f2b(rah[it].x); o[5] = f2b(rah[it].y);
                o[6] = f2b(rah[it].z); o[7] = f2b(rah[it].w);
                *reinterpret_cast<u16x8*>(&Asl[(it * 32 + srow) * 72 + skc]) = o;
            } else {
                if (gA2) {
                    u16x8 o;
                    #pragma unroll
                    for (int e = 0; e < 8; ++e)
                        o[e] = f2b(b2f((u16)rab[it][e]) + b2f((u16)rab2[it][e]));
                    *reinterpret_cast<u16x8*>(&Asl[(it * 32 + srow) * 72 + skc]) = o;
                } else {
                    *reinterpret_cast<bf16x8*>(&Asl[(it * 32 + srow) * 72 + skc]) = rab[it];
                }
            }
            *reinterpret_cast<bf16x8*>(&Bsl[(it * 32 + srow) * 72 + skc]) = rw[it];
        }
        if (t < 7) {
            const int k0 = (t + 1) * 64;
            #pragma unroll
            for (int it = 0; it < 4; ++it) {
                if constexpr (F32) {
                    ral[it] = *reinterpret_cast<const float4*>(gA + k0 + (size_t)it * 32 * 512);
                    rah[it] = *reinterpret_cast<const float4*>(gA + k0 + (size_t)it * 32 * 512 + 4);
                } else {
                    rab[it] = *reinterpret_cast<const bf16x8*>(gA + k0 + (size_t)it * 32 * 512);
                    if (gA2) rab2[it] = *reinterpret_cast<const bf16x8*>(gA2 + k0 + (size_t)it * 32 * 512);
                }
                rw[it] = *reinterpret_cast<const bf16x8*>(gB + k0 + (size_t)it * 32 * 512);
            }
        }
        __syncthreads();
        #pragma unroll
        for (int ks = 0; ks < 2; ++ks) {
            bf16x8 af[4], bf_[4];
            #pragma unroll
            for (int mi = 0; mi < 4; ++mi)
                af[mi] = *reinterpret_cast<const bf16x8*>(&Asl[(wr + mi * 16 + lr) * 72 + ks * 32 + lk]);
            #pragma unroll
            for (int ni = 0; ni < 4; ++ni)
                bf_[ni] = *reinterpret_cast<const bf16x8*>(&Bsl[(wc + ni * 16 + lr) * 72 + ks * 32 + lk]);
            #pragma unroll
            for (int mi = 0; mi < 4; ++mi)
                #pragma unroll
                for (int ni = 0; ni < 4; ++ni)
                    acc[mi][ni] = mfma16(af[mi], bf_[ni], acc[mi][ni]);
        }
        __syncthreads();
    }
}

// ---------------------------------------------------------------------------
// QKV GEMM body with coalesced epilogues. q/k: restage via LDS [128][136],
// then 8 lanes cover a 128B row run (full cachelines). v: LDS transpose then
// 8-threads-per-row 16B writes.
// ---------------------------------------------------------------------------
template<typename AT>
__device__ __forceinline__ void qkv_body(
    const AT* __restrict__ A, const u16* __restrict__ Wt,
    u16* __restrict__ qb, u16* __restrict__ kb, u16* __restrict__ vt,
    int sl, int rb, int cb)
{
    __shared__ __align__(16) short Ls[2 * 128 * 72];
    short* Asl = Ls;
    short* Bsl = Ls + 128 * 72;
    f32x4 acc[4][4] = {};
    gemm_core_128<AT>(A, nullptr, Wt, rb, cb, Asl, Bsl, acc);
    const int tid = threadIdx.x;
    const int wave = tid >> 6, lane = tid & 63;
    const int lr = lane & 15, lg = lane >> 4;
    const int wr = (wave >> 1) * 64, wc = (wave & 1) * 64;
    const int seq = 1 << sl, smask = seq - 1;
    if (cb < 1024) {
        const float scl = (cb < 512) ? 0.125f : 1.0f;
        #pragma unroll
        for (int mi = 0; mi < 4; ++mi)
            #pragma unroll
            for (int ni = 0; ni < 4; ++ni) {
                int row = wr + mi * 16 + lg * 4;
                int col = wc + ni * 16 + lr;
                f32x4 v = acc[mi][ni];
                #pragma unroll
                for (int j = 0; j < 4; ++j)
                    Ls[(row + j) * 136 + col] = (short)f2b(v[j] * scl);
            }
        __syncthreads();
        u16* dst = (cb < 512) ? qb : kb;
        if (dst) {
            const int cbase = (cb < 512) ? cb : cb - 512;
            #pragma unroll
            for (int p = 0; p < 8; ++p) {
                int slot = p * 256 + tid;
                int row = slot >> 4;
                int half = (slot >> 3) & 1;
                int inner = slot & 7;
                int m = rb + row;
                int bb = m >> sl, n = m & smask;
                int cg = cbase + half * 64;
                int h = cg >> 6;
                u16x8 val = *reinterpret_cast<u16x8*>(&Ls[row * 136 + half * 64 + inner * 8]);
                *reinterpret_cast<u16x8*>(
                    &dst[(((size_t)bb * HH + h) * seq + n) * 64 + inner * 8]) = val;
            }
        }
    } else {
        #pragma unroll
        for (int mi = 0; mi < 4; ++mi)
            #pragma unroll
            for (int ni = 0; ni < 4; ++ni) {
                int col = wc + ni * 16 + lr;
                int row0 = wr + mi * 16 + lg * 4;
                f32x4 v = acc[mi][ni];
                #pragma unroll
                for (int j = 0; j < 4; ++j)
                    Ls[col * 136 + row0 + j] = (short)f2b(v[j]);
            }
        __syncthreads();
        const int bb = rb >> sl, n0 = rb & smask;
        #pragma unroll
        for (int p = 0; p < 4; ++p) {
            int slot = p * 256 + tid;
            int col = slot >> 3;
            int inner = slot & 7;
            int dg = (cb - 1024) + col;
            int h = dg >> 6, d = dg & 63;
            u16* vrow = vt + ((((size_t)bb * HH + h) * 64 + d) << sl) + n0;
            u16x8 v0 = *reinterpret_cast<u16x8*>(&Ls[col * 136 + inner * 8]);
            u16x8 v1 = *reinterpret_cast<u16x8*>(&Ls[col * 136 + 64 + inner * 8]);
            *reinterpret_cast<u16x8*>(vrow + inner * 8) = v0;
            *reinterpret_cast<u16x8*>(vrow + 64 + inner * 8) = v1;
        }
    }
}

// All 4 first-stage QKV GEMMs (f32 input, cast fused): 960 blocks, XCD swizzle
__global__ __launch_bounds__(256, 3) void gemm_qkv_all_k(
    const float* __restrict__ A0, const float* __restrict__ A1,
    const float* __restrict__ A2, const float* __restrict__ A3,
    const u16* __restrict__ W01, const u16* __restrict__ W23,
    u16* q0, u16* k0, u16* v0, u16* q1, u16* k1, u16* v1,
    u16* q2, u16* k2, u16* v2, u16* q3, u16* k3, u16* v3)
{
    const int lin = blockIdx.x;
    const int swz = (lin & 7) * 120 + (lin >> 3);
    const int x = swz % 12, y = swz / 12;
    const float* A; const u16* Wt; u16 *qb, *kb, *vt; int sl, ry;
    if (y < 32)      { A = A0; Wt = W01; qb = q0; kb = k0; vt = v0; sl = 10; ry = y; }
    else if (y < 40) { A = A1; Wt = W01; qb = q1; kb = k1; vt = v1; sl = 8;  ry = y - 32; }
    else if (y < 72) { A = A2; Wt = W23; qb = q2; kb = k2; vt = v2; sl = 10; ry = y - 40; }
    else             { A = A3; Wt = W23; qb = q3; kb = k3; vt = v3; sl = 8;  ry = y - 72; }
    qkv_body<float>(A, Wt, qb, kb, vt, sl, ry * 128, x * 128);
}

// Second-stage QKV GEMM (IKOUT, bf16 input): only k/v columns (x offset +4)
__global__ __launch_bounds__(256, 3) void gemm_qkv2_k(
    const u16* __restrict__ A, const u16* __restrict__ Wt,
    u16* kb, u16* vt)
{
    qkv_body<u16>(A, Wt, nullptr, kb, vt, 8, blockIdx.y * 128, (blockIdx.x + 4) * 128);
}

// ---------------------------------------------------------------------------
// Proj GEMM body (pipelined core, bf16 A, optional A2 summed) + bias epilogue
// ---------------------------------------------------------------------------
template<bool OUTBF>
__device__ __forceinline__ void proj_body(
    const u16* __restrict__ A, const u16* __restrict__ A2,
    const u16* __restrict__ Wt,
    const float* __restrict__ bias, float bscale, void* __restrict__ outp,
    int rb, int cb)
{
    __shared__ __align__(16) short Ls[2 * 128 * 72];
    f32x4 acc[4][4] = {};
    gemm_core_128<u16>(A, A2, Wt, rb, cb, Ls, Ls + 128 * 72, acc);
    const int tid = threadIdx.x;
    const int wave = tid >> 6, lane = tid & 63;
    const int lr = lane & 15;
    const int wr = (wave >> 1) * 64, wc = (wave & 1) * 64;
    #pragma unroll
    for (int mi = 0; mi < 4; ++mi) {
        int m0 = rb + wr + mi * 16 + (lane >> 4) * 4;
        #pragma unroll
        for (int ni = 0; ni < 4; ++ni) {
            int c = cb + wc + ni * 16 + lr;
            float bv = bscale * bias[c];
            f32x4 v = acc[mi][ni];
            #pragma unroll
            for (int j = 0; j < 4; ++j) {
                size_t o = (size_t)(m0 + j) * 512 + c;
                if (OUTBF) reinterpret_cast<u16*>(outp)[o] = f2b(v[j] + bv);
                else       reinterpret_cast<float*>(outp)[o] = v[j] + bv;
            }
        }
    }
}

// single proj (IKOUT, bf16 out)
__global__ __launch_bounds__(256, 3) void gemm_proj_bf16_k(
    const u16* __restrict__ A, const u16* __restrict__ Wt,
    const float* __restrict__ bias, float bscale, u16* __restrict__ outp)
{
    proj_body<true>(A, nullptr, Wt, bias, bscale, outp, blockIdx.y * 128, blockIdx.x * 128);
}

// final combined proj: 288 linear blocks (128 x_out [dual-A], 128 i_x_out, 32 k_out)
__global__ __launch_bounds__(256, 3) void gemm_proj3_k(
    const u16* __restrict__ A0, const u16* __restrict__ A0b,
    const u16* __restrict__ A1, const u16* __restrict__ A2,
    const u16* __restrict__ W, const u16* __restrict__ Wi2,
    const float* __restrict__ bp, const float* __restrict__ bpi2,
    float* __restrict__ o0, float* __restrict__ o1, float* __restrict__ o2)
{
    const int id = blockIdx.x;
    const u16 *A, *Ax; const u16* Wt; const float* bias; float bscale; float* outp; int x, y;
    if (id < 128)      { A = A0; Ax = A0b; Wt = W;   bias = bp;   bscale = 2.0f; outp = o0; x = id & 3; y = id >> 2; }
    else if (id < 256) { A = A1; Ax = nullptr; Wt = Wi2; bias = bpi2; bscale = 1.0f; outp = o1; x = (id - 128) & 3; y = (id - 128) >> 2; }
    else               { A = A2; Ax = nullptr; Wt = W;   bias = bp;   bscale = 1.0f; outp = o2; x = (id - 256) & 3; y = (id - 256) >> 2; }
    proj_body<false>(A, Ax, Wt, bias, bscale, outp, y * 128, x * 128);
}

// ---------------------------------------------------------------------------
// Paired wide scores with coalesced S epilogue via LDS restage.
// z<32 -> (KQ,KX)->SPa ; else (IKQ,IK)->SPb. R=256,C=1024.
// ---------------------------------------------------------------------------
__global__ __launch_bounds__(256, 4) void scores_pair_k(
    const u16* __restrict__ A1, const u16* __restrict__ B1, u16* __restrict__ S1,
    const u16* __restrict__ A2, const u16* __restrict__ B2, u16* __restrict__ S2)
{
    __shared__ __align__(16) short Ls[2 * 128 * 72];
    short* As = Ls;
    short* Bs = Ls + 128 * 72;
    const int z = blockIdx.z, bh = z & 31;
    const u16* Aq = (z < 32) ? A1 : A2;
    const u16* Bk = (z < 32) ? B1 : B2;
    u16* S = (z < 32) ? S1 : S2;
    const int tid = threadIdx.x;
    const int wave = tid >> 6, lane = tid & 63;
    const int lr = lane & 15, lg = lane >> 4, lk = lg * 8;
    const int rb = blockIdx.y * 128, cb = blockIdx.x * 128;
    const int wr = (wave >> 1) * 64, wc = (wave & 1) * 64;
    const u16* Ap = Aq + (size_t)bh * 256 * 64;
    const u16* Bp = Bk + (size_t)bh * 1024 * 64;
    const int srow = tid >> 3, skc = (tid & 7) * 8;
    #pragma unroll
    for (int it = 0; it < 4; ++it) {
        int row = it * 32 + srow;
        *reinterpret_cast<bf16x8*>(&As[row * 72 + skc]) =
            *reinterpret_cast<const bf16x8*>(Ap + (size_t)(rb + row) * 64 + skc);
        *reinterpret_cast<bf16x8*>(&Bs[row * 72 + skc]) =
            *reinterpret_cast<const bf16x8*>(Bp + (size_t)(cb + row) * 64 + skc);
    }
    __syncthreads();
    f32x4 acc[4][4] = {};
    #pragma unroll
    for (int ks = 0; ks < 2; ++ks) {
        bf16x8 af[4], bf_[4];
        #pragma unroll
        for (int mi = 0; mi < 4; ++mi)
            af[mi] = *reinterpret_cast<const bf16x8*>(&As[(wr + mi * 16 + lr) * 72 + ks * 32 + lk]);
        #pragma unroll
        for (int ni = 0; ni < 4; ++ni)
            bf_[ni] = *reinterpret_cast<const bf16x8*>(&Bs[(wc + ni * 16 + lr) * 72 + ks * 32 + lk]);
        #pragma unroll
        for (int mi = 0; mi < 4; ++mi)
            #pragma unroll
            for (int ni = 0; ni < 4; ++ni)
                acc[mi][ni] = mfma16(af[mi], bf_[ni], acc[mi][ni]);
    }
    __syncthreads();   // all LDS reads done -> reuse Ls as [128][136] epilogue buffer
    #pragma unroll
    for (int mi = 0; mi < 4; ++mi)
        #pragma unroll
        for (int ni = 0; ni < 4; ++ni) {
            int row = wr + mi * 16 + lg * 4;
            int col = wc + ni * 16 + lr;
            f32x4 v = acc[mi][ni];
            #pragma unroll
            for (int j = 0; j < 4; ++j)
                Ls[(row + j) * 136 + col] = (short)f2b(v[j]);
        }
    __syncthreads();
    #pragma unroll
    for (int p = 0; p < 8; ++p) {
        int slot = p * 256 + tid;
        int row = slot >> 4;
        int chunk = slot & 15;
        u16x8 val = *reinterpret_cast<u16x8*>(&Ls[row * 136 + chunk * 8]);
        *reinterpret_cast<u16x8*>(
            &S[((size_t)bh * 256 + rb + row) * 1024 + cb + chunk * 8]) = val;
    }
}

// ---------------------------------------------------------------------------
// Paired wide softmax: rows [0,8192) -> SPa + bf16 bias1 ; [8192,16384) ->
// SPb + u8 maskT (-1e9).
// ---------------------------------------------------------------------------
__global__ __launch_bounds__(256) void softmax_pair_k(
    u16* __restrict__ S1, const u16* __restrict__ bias1,
    u16* __restrict__ S2, const unsigned char* __restrict__ maskT)
{
    const int rg = blockIdx.x;
    const bool first = rg < 8192;
    const int row_g = first ? rg : rg - 8192;
    const int tid = threadIdx.x;
    const int wave = tid >> 6, lane = tid & 63;
    const int c = tid * 4;
    u16* rowp = (first ? S1 : S2) + (size_t)row_g * 1024;
    ushort4 sv = *reinterpret_cast<const ushort4*>(rowp + c);
    float s[4] = { b2f(sv.x), b2f(sv.y), b2f(sv.z), b2f(sv.w) };
    if (first) {
        ushort4 bv = *reinterpret_cast<const ushort4*>(bias1 + (size_t)row_g * 1024 + c);
        s[0] += b2f(bv.x); s[1] += b2f(bv.y); s[2] += b2f(bv.z); s[3] += b2f(bv.w);
    } else {
        uchar4 mk = *reinterpret_cast<const uchar4*>(maskT + (size_t)row_g * 1024 + c);
        if (mk.x) s[0] = -1e9f; if (mk.y) s[1] = -1e9f;
        if (mk.z) s[2] = -1e9f; if (mk.w) s[3] = -1e9f;
    }
    __shared__ float swv[4];
    float lm = fmaxf(fmaxf(s[0], s[1]), fmaxf(s[2], s[3]));
    lm = wred_max(lm);
    if (lane == 0) swv[wave] = lm;
    __syncthreads();
    float m = fmaxf(fmaxf(swv[0], swv[1]), fmaxf(swv[2], swv[3]));
    __syncthreads();
    float ls = 0.0f;
    #pragma unroll
    for (int j = 0; j < 4; ++j) { s[j] = __expf(s[j] - m); ls += s[j]; }
    ls = wred_sum(ls);
    if (lane == 0) swv[wave] = ls;
    __syncthreads();
    float inv = 1.0f / (swv[0] + swv[1] + swv[2] + swv[3]);
    ushort4 ov = { f2b(s[0] * inv), f2b(s[1] * inv), f2b(s[2] * inv), f2b(s[3] * inv) };
    *reinterpret_cast<ushort4*>(rowp + c) = ov;
}

// ---------------------------------------------------------------------------
// Paired PV with coalesced per-wave epilogue. z=0: (SPa,VXt)->KMb ;
// z=1: (SPb,IVt)->KMb2
// ---------------------------------------------------------------------------
__global__ __launch_bounds__(256, 4) void pv_pair_k(
    const u16* __restrict__ P1, const u16* __restrict__ V1, u16* __restrict__ o1,
    const u16* __restrict__ P2, const u16* __restrict__ V2, u16* __restrict__ o2)
{
    __shared__ __align__(16) short Ps[4 * 16 * 72];
    const int z = blockIdx.z;
    const u16* P = z ? P2 : P1;
    const u16* V = z ? V2 : V1;
    u16* out = z ? o2 : o1;
    const int tid = threadIdx.x;
    const int wave = tid >> 6, lane = tid & 63;
    const int lr = lane & 15, lg = lane >> 4, lk = lg * 8;
    const int bh = blockIdx.y, b = bh >> 3, h = bh & 7;
    const int rb = blockIdx.x * 64;
    const int wr = wave * 16;
    f32x4 acc[4] = {};
    const u16* Pb = P + ((size_t)bh * 256 + rb) * 1024;
    const u16* Vb = V + (size_t)bh * 64 * 1024;
    for (int c0 = 0; c0 < 1024; c0 += 64) {
        #pragma unroll
        for (int ks = 0; ks < 2; ++ks) {
            bf16x8 ap = *reinterpret_cast<const bf16x8*>(
                Pb + (size_t)(wr + lr) * 1024 + c0 + ks * 32 + lk);
            #pragma unroll
            for (int ni = 0; ni < 4; ++ni) {
                bf16x8 vv = *reinterpret_cast<const bf16x8*>(
                    Vb + (size_t)(ni * 16 + lr) * 1024 + c0 + ks * 32 + lk);
                acc[ni] = mfma16(ap, vv, acc[ni]);
            }
        }
    }
    short* myP = &Ps[wave * 16 * 72];
    #pragma unroll
    for (int ni = 0; ni < 4; ++ni) {
        int d = ni * 16 + lr;
        f32x4 v = acc[ni];
        #pragma unroll
        for (int j = 0; j < 4; ++j)
            myP[(lg * 4 + j) * 72 + d] = (short)f2b(v[j]);
    }
    #pragma unroll
    for (int p = 0; p < 2; ++p) {
        int slot = p * 64 + lane;
        int rloc = slot >> 3;
        int inner = slot & 7;
        int r0 = rb + wr + rloc;
        u16x8 val = *reinterpret_cast<u16x8*>(&myP[rloc * 72 + inner * 8]);
        *reinterpret_cast<u16x8*>(
            &out[((size_t)(b * 256 + r0)) * 512 + h * 64 + inner * 8]) = val;
    }
}

// ---------------------------------------------------------------------------
// Merged fused attention: 1536 blocks.
//  [0,512)    : branch2 src0 (Q, KK, KVt, biasF bf16)  -> XMb
//  [512,1024) : branch2 src1 (Q, IKK, IKVt, crossB8 u8)-> XMc
//  [1024,1536): branch3     (IQ, K2K, K2Vt, iattB8 u8) -> XMb2
// u8 masks are expanded to bf16 {0,-1e9} AT LOAD into the single breg path,
// so only one register set lives (no spills). 64 rows/block, 4 waves.
// ---------------------------------------------------------------------------
__global__ __launch_bounds__(256, 4) void attn_all_k(
    const u16* __restrict__ Q0, const u16* __restrict__ IQ0,
    const u16* __restrict__ K1, const u16* __restrict__ V1t,
    const u16* __restrict__ B1F, u16* __restrict__ out1,
    const u16* __restrict__ K2, const u16* __restrict__ V2t,
    const unsigned char* __restrict__ B2M, u16* __restrict__ out2,
    const u16* __restrict__ K3, const u16* __restrict__ V3t,
    const unsigned char* __restrict__ B3M, u16* __restrict__ out3)
{
    const int tid = threadIdx.x;
    const int w = tid >> 6, lane = tid & 63;
    const int lr = lane & 15, lg = lane >> 4, lk = lg * 8;
    int lin = blockIdx.x;
    const u16 *Qp, *Kp, *Vp; const u16* BF = nullptr;
    const unsigned char* BM = nullptr; u16* outm;
    if (lin < 512)        { Qp = Q0;  Kp = K1; Vp = V1t; BF = B1F; outm = out1; }
    else if (lin < 1024)  { Qp = Q0;  Kp = K2; Vp = V2t; BM = B2M; outm = out2; lin -= 512; }
    else                  { Qp = IQ0; Kp = K3; Vp = V3t; BM = B3M; outm = out3; lin -= 1024; }
    const int xcd = lin & 7, idx = lin >> 3;
    const int bh = xcd * 4 + (idx & 3);
    const int rb = (idx >> 2) * 64;
    const int b = bh >> 3, h = bh & 7;
    const int wr = w * 16;
    const int strip = (rb >> 4) + w;

    __shared__ __align__(16) short Ps[4 * 16 * 264];   // per-wave scratch
    short* myP = &Ps[w * 16 * 264];

    bf16x8 qf0, qf1;
    {
        const u16* Qb = Qp + ((size_t)bh * 1024 + rb + wr + lr) * 64;
        qf0 = *reinterpret_cast<const bf16x8*>(Qb + lk);
        qf1 = *reinterpret_cast<const bf16x8*>(Qb + 32 + lk);
    }

    // bias prefetch into the SINGLE breg path: bf16 loads (seg0) or u8 mask
    // loads expanded at once to bf16 {0, -1e9} (seg1/2).
    bf16x8 breg[8];
    {
        const u16 NEG9 = f2b(-1e9f);
        if (BF) {
            const u16* bb = BF + (((size_t)bh * 64 + strip) * 8) * 512 + (size_t)lane * 8;
            #pragma unroll
            for (int itp = 0; itp < 8; ++itp)
                breg[itp] = *reinterpret_cast<const bf16x8*>(bb + (size_t)itp * 512);
        } else {
            const unsigned char* bb = BM + (((size_t)bh * 64 + strip) * 8) * 512 + (size_t)lane * 8;
            #pragma unroll
            for (int itp = 0; itp < 8; ++itp) {
                u64 m = *reinterpret_cast<const u64*>(bb + (size_t)itp * 512);
                bf16x8 r;
                #pragma unroll
                for (int e = 0; e < 8; ++e)
                    r[e] = (short)(((m >> (e * 8)) & 0xFFull) ? NEG9 : (u16)0);
                breg[itp] = r;
            }
        }
    }
    // scores: 16 rows x 256 cols per wave; K direct from global (L2)
    const u16* Kb = Kp + (size_t)bh * 256 * 64;
    f32x4 acc[16];
    #pragma unroll
    for (int ni = 0; ni < 16; ++ni) acc[ni] = (f32x4){0.f, 0.f, 0.f, 0.f};
    #pragma unroll
    for (int ni = 0; ni < 16; ++ni) {
        bf16x8 b0 = *reinterpret_cast<const bf16x8*>(Kb + (size_t)(ni * 16 + lr) * 64 + lk);
        acc[ni] = mfma16(qf0, b0, acc[ni]);
    }
    #pragma unroll
    for (int ni = 0; ni < 16; ++ni) {
        bf16x8 b1 = *reinterpret_cast<const bf16x8*>(Kb + (size_t)(ni * 16 + lr) * 64 + 32 + lk);
        acc[ni] = mfma16(qf1, b1, acc[ni]);
    }
    // bias from regs + in-wave softmax (single uniform path)
    float mx[4] = { -3.4e38f, -3.4e38f, -3.4e38f, -3.4e38f };
    #pragma unroll
    for (int ni = 0; ni < 16; ++ni) {
        const bf16x8 br = breg[ni >> 1];
        #pragma unroll
        for (int j = 0; j < 4; ++j) {
            float v = acc[ni][j] + b2f((u16)br[(ni & 1) * 4 + j]);
            acc[ni][j] = v;
            mx[j] = fmaxf(mx[j], v);
        }
    }
    #pragma unroll
    for (int j = 0; j < 4; ++j) {
        #pragma unroll
        for (int o = 1; o < 16; o <<= 1) mx[j] = fmaxf(mx[j], __shfl_xor(mx[j], o, 64));
    }
    float sm[4] = {};
    #pragma unroll
    for (int ni = 0; ni < 16; ++ni) {
        #pragma unroll
        for (int j = 0; j < 4; ++j) {
            float e = __expf(acc[ni][j] - mx[j]);
            acc[ni][j] = e;
            sm[j] += e;
        }
    }
    #pragma unroll
    for (int j = 0; j < 4; ++j) {
        #pragma unroll
        for (int o = 1; o < 16; o <<= 1) sm[j] += __shfl_xor(sm[j], o, 64);
        sm[j] = 1.0f / sm[j];
    }
    // P to wave-local LDS (in-wave transpose), then PV with V from global
    #pragma unroll
    for (int ni = 0; ni < 16; ++ni)
        #pragma unroll
        for (int j = 0; j < 4; ++j)
            myP[(lg * 4 + j) * 264 + ni * 16 + lr] = (short)f2b(acc[ni][j] * sm[j]);
    f32x4 acc2[4] = {};
    #pragma unroll
    for (int kc = 0; kc < 8; ++kc) {
        bf16x8 ap = *reinterpret_cast<const bf16x8*>(&myP[lr * 264 + kc * 32 + lk]);
        #pragma unroll
        for (int ni = 0; ni < 4; ++ni) {
            bf16x8 vv = *reinterpret_cast<const bf16x8*>(
                Vp + ((size_t)bh * 64 + ni * 16 + lr) * 256 + kc * 32 + lk);
            acc2[ni] = mfma16(ap, vv, acc2[ni]);
        }
    }
    // coalesced epilogue: restage 16x64 tile (stride 72), 8 lanes per 128B row
    #pragma unroll
    for (int ni = 0; ni < 4; ++ni) {
        int d = ni * 16 + lr;
        f32x4 v = acc2[ni];
        #pragma unroll
        for (int j = 0; j < 4; ++j)
            myP[(lg * 4 + j) * 72 + d] = (short)f2b(v[j]);
    }
    #pragma unroll
    for (int p = 0; p < 2; ++p) {
        int slot = p * 64 + lane;
        int rloc = slot >> 3;
        int inner = slot & 7;
        int row = rb + wr + rloc;
        u16x8 val = *reinterpret_cast<u16x8*>(&myP[rloc * 72 + inner * 8]);
        *reinterpret_cast<u16x8*>(
            &outm[((size_t)(b * 1024 + row)) * 512 + h * 64 + inner * 8]) = val;
    }
}

// ---------------------------------------------------------------------------
extern "C" void kernel_launch(void* const* d_in, const int* in_sizes, int n_in,
                              void* d_out, int out_size, void* d_ws, size_t ws_size,
                              hipStream_t stream)
{
    const float* x        = (const float*)d_in[0];
    const float* kernal   = (const float*)d_in[1];
    const float* i_x      = (const float*)d_in[2];
    const float* i_kernal = (const float*)d_in[3];
    const int*   rd       = (const int*)d_in[4];
    const int*   polar    = (const int*)d_in[5];
    const int*   att      = (const int*)d_in[6];
    const int*   i_att    = (const int*)d_in[7];
    const int*   cross    = (const int*)d_in[8];
    const float* Wqkv     = (const float*)d_in[9];
    const float* Wqkv_i   = (const float*)d_in[10];
    const float* Wqkv_i2  = (const float*)d_in[11];
    const float* Wproj    = (const float*)d_in[12];
    const float* bproj    = (const float*)d_in[13];
    const float* Wproj_i  = (const float*)d_in[14];
    const float* bproj_i  = (const float*)d_in[15];
    const float* Wproj_i2 = (const float*)d_in[16];
    const float* bproj_i2 = (const float*)d_in[17];
    const float* dis      = (const float*)d_in[18];
    const float* pemb     = (const float*)d_in[19];

    float* out = (float*)d_out;
    float* x_out   = out;
    float* k_out   = out + (size_t)BB * XLL * DIMM;
    float* i_x_out = k_out + (size_t)BB * KLL * DIMM;

    char* ws = (char*)d_ws;
    size_t off = 0;
    auto alloc = [&](size_t bytes) { void* p = ws + off; off += (bytes + 255) & ~(size_t)255; return p; };

    const size_t NAX = (size_t)BB * XLL * DIMM;
    const size_t NAK = (size_t)BB * KLL * DIMM;
    const size_t NHX = (size_t)BHH * XLL * HEADD;
    const size_t NHK = (size_t)BHH * KLL * HEADD;
    const size_t NS  = (size_t)BHH * KLL * XLL;

    u16* WqkvT    = (u16*)alloc((size_t)1536 * 512 * 2);
    u16* WqkvIT   = (u16*)alloc((size_t)1536 * 512 * 2);
    u16* WqkvI2T  = (u16*)alloc((size_t)1536 * 512 * 2);
    u16* WprojT   = (u16*)alloc((size_t)512 * 512 * 2);
    u16* WprojIT  = (u16*)alloc((size_t)512 * 512 * 2);
    u16* WprojI2T = (u16*)alloc((size_t)512 * 512 * 2);
    u16* Q    = (u16*)alloc(NHX * 2);
    u16* KX   = (u16*)alloc(NHX * 2);
    u16* VXt  = (u16*)alloc(NHX * 2);
    u16* IQ   = (u16*)alloc(NHX * 2);
    u16* IK   = (u16*)alloc(NHX * 2);
    u16* IVt  = (u16*)alloc(NHX * 2);
    u16* KQ   = (u16*)alloc(NHK * 2);
    u16* KK   = (u16*)alloc(NHK * 2);
    u16* KVt  = (u16*)alloc(NHK * 2);
    u16* IKQ  = (u16*)alloc(NHK * 2);
    u16* IKK  = (u16*)alloc(NHK * 2);
    u16* IKVt = (u16*)alloc(NHK * 2);
    u16* K2K  = (u16*)alloc(NHK * 2);
    u16* K2Vt = (u16*)alloc(NHK * 2);
    u16* SPa  = (u16*)alloc(NS * 2);
    u16* SPb  = (u16*)alloc(NS * 2);
    u16* KMb  = (u16*)alloc(NAK * 2);
    u16* KMb2 = (u16*)alloc(NAK * 2);
    u16* XMb  = (u16*)alloc(NAX * 2);
    u16* XMb2 = (u16*)alloc(NAX * 2);
    u16* XMc  = (u16*)alloc(NAX * 2);
    u16* IKOUTb = (u16*)alloc(NAK * 2);
    u16* biasF = (u16*)alloc(NS * 2);
    u16* bias1 = (u16*)alloc(NS * 2);
    unsigned char* crossB8 = (unsigned char*)alloc(NS);
    unsigned char* iattB8  = (unsigned char*)alloc(NS);
    unsigned char* iattT8  = (unsigned char*)alloc(NS);
    int* MO   = (int*)alloc((size_t)BHH * KLL * 4);

    dim3 blk(256);

    // 1. merged prep (weight transposes + mask conversions, u8 frag masks)
    prep_all_k<<<dim3(19456), blk, 0, stream>>>(
        Wqkv, Wqkv_i, Wqkv_i2, Wproj, Wproj_i, Wproj_i2,
        WqkvT, WqkvIT, WqkvI2T, WprojT, WprojIT, WprojI2T,
        i_att, iattT8, iattB8, cross, crossB8);

    // 2. all first-stage QKV GEMMs (cast fused, q pre-scaled), XCD-swizzled
    gemm_qkv_all_k<<<dim3(960), blk, 0, stream>>>(
        x, kernal, i_x, i_kernal, WqkvT, WqkvIT,
        Q, KX, VXt, KQ, KK, KVt, IQ, IK, IVt, IKQ, IKK, IKVt);

    // 3. wide scores (branch1 + branch3)
    scores_pair_k<<<dim3(8, 2, 64), blk, 0, stream>>>(KQ, KX, SPa, IKQ, IK, SPb);
    // 4. main orientation + bias builds
    main_ori_k8<<<dim3(BB * KLL), blk, 0, stream>>>(SPa, polar, MO);
    bias_build_k<<<dim3(32, 8, BB), blk, 0, stream>>>(rd, polar, att, dis, pemb, MO, biasF, bias1);
    // 5. wide softmaxes
    softmax_pair_k<<<dim3(16384), blk, 0, stream>>>(SPa, bias1, SPb, iattT8);
    // 6. wide PVs (barrier-free)
    pv_pair_k<<<dim3(4, 32, 2), blk, 0, stream>>>(SPa, VXt, KMb, SPb, IVt, KMb2);
    // 7. IKOUT proj (bf16) + second qkv (k/v columns only)
    gemm_proj_bf16_k<<<dim3(4, 8), blk, 0, stream>>>(KMb2, WprojIT, bproj_i, 1.0f, IKOUTb);
    gemm_qkv2_k<<<dim3(8, 8), blk, 0, stream>>>(IKOUTb, WqkvI2T, K2K, K2Vt);
    // 8. all three fused attentions in one launch (1536 blocks)
    attn_all_k<<<dim3(1536), blk, 0, stream>>>(
        Q, IQ, KK, KVt, biasF, XMb, IKK, IKVt, crossB8, XMc,
        K2K, K2Vt, iattB8, XMb2);
    // 9. final combined projections (x_out = (XMb+XMc)@W, i_x_out, k_out)
    gemm_proj3_k<<<dim3(288), blk, 0, stream>>>(
        XMb, XMc, XMb2, KMb, WprojT, WprojI2T, bproj, bproj_i2, x_out, i_x_out, k_out);

    (void)in_sizes; (void)n_in; (void)out_size; (void)ws_size;
}

// Round 20
// 257.122 us; speedup vs baseline: 1.1289x; 1.0144x over previous
//
#include <hip/hip_runtime.h>
#include <cstddef>
#include <cstdint>

#define BB 4
#define HH 8
#define HEADD 64
#define DIMM 512
#define XLL 1024
#define KLL 256
#define BHH (BB*HH)

typedef __attribute__((ext_vector_type(8))) short bf16x8;
typedef __attribute__((ext_vector_type(8))) unsigned short u16x8;
typedef __attribute__((ext_vector_type(4))) float f32x4;
typedef unsigned short u16;

__device__ __forceinline__ u16 f2b(float f) {
    unsigned int u = __builtin_bit_cast(unsigned int, f);
    u = u + 0x7fffu + ((u >> 16) & 1u);
    return (u16)(u >> 16);
}
__device__ __forceinline__ float b2f(u16 h) {
    unsigned int u = ((unsigned int)h) << 16;
    return __builtin_bit_cast(float, u);
}
__device__ __forceinline__ f32x4 mfma16(bf16x8 a, bf16x8 b, f32x4 c) {
    return __builtin_amdgcn_mfma_f32_16x16x32_bf16(a, b, c, 0, 0, 0);
}
__device__ __forceinline__ float wred_max(float v) {
    #pragma unroll
    for (int o = 1; o < 64; o <<= 1) v = fmaxf(v, __shfl_xor(v, o, 64));
    return v;
}
__device__ __forceinline__ float wred_sum(float v) {
    #pragma unroll
    for (int o = 1; o < 64; o <<= 1) v += __shfl_xor(v, o, 64);
    return v;
}

// Fragment-order bias layout:
//   E(bh,x,k) = ((bh*64 + (x>>4))*8 + (k>>5))*512
//             + (((x>>2)&3)*16 + (k&15))*8 + ((k>>4)&1)*4 + (x&3)

// ---------------------------------------------------------------------------
// Merged prep: blocks [0,3072) = 6 weight transposes (f32 [K][N]->bf16 [N][K]);
// blocks [3072,19456) = mask prep (i_att -> iattT8+iattBF ; cross -> crossBF)
// ---------------------------------------------------------------------------
__global__ __launch_bounds__(256) void prep_all_k(
    const float* __restrict__ s0, const float* __restrict__ s1,
    const float* __restrict__ s2, const float* __restrict__ s3,
    const float* __restrict__ s4, const float* __restrict__ s5,
    u16* __restrict__ d0, u16* __restrict__ d1, u16* __restrict__ d2,
    u16* __restrict__ d3, u16* __restrict__ d4, u16* __restrict__ d5,
    const int* __restrict__ i_att, unsigned char* __restrict__ iattT8,
    u16* __restrict__ iattBF,
    const int* __restrict__ cross, u16* __restrict__ crossBF)
{
    const int id = blockIdx.x;
    if (id < 3072) {
        __shared__ float t[32][33];
        const float* W; u16* Wt; int N, bx, by;
        if (id < 2304) {
            int which = id / 768, local = id - which * 768;
            W = which == 0 ? s0 : (which == 1 ? s1 : s2);
            Wt = which == 0 ? d0 : (which == 1 ? d1 : d2);
            N = 1536; bx = local % 48; by = local / 48;
        } else {
            int which = (id - 2304) / 256, local = (id - 2304) % 256;
            W = which == 0 ? s3 : (which == 1 ? s4 : s5);
            Wt = which == 0 ? d3 : (which == 1 ? d4 : d5);
            N = 512; bx = local % 16; by = local / 16;
        }
        const int K = 512;
        int tx = threadIdx.x & 31, ty = threadIdx.x >> 5;
        #pragma unroll
        for (int r = ty; r < 32; r += 8)
            t[r][tx] = W[(size_t)(by * 32 + r) * N + bx * 32 + tx];
        __syncthreads();
        #pragma unroll
        for (int r = ty; r < 32; r += 8)
            Wt[(size_t)(bx * 32 + r) * K + by * 32 + tx] = f2b(t[tx][r]);
        return;
    }
    const int id2 = id - 3072;
    const int xt = id2 & 31, kt = (id2 >> 5) & 7, z = id2 >> 8;
    const int bh = z & 31;
    const int tid = threadIdx.x;
    const u16 NEG = f2b(-1e9f);
    const int sl = tid >> 7, rem = tid & 127, l = rem >> 1, nilow = rem & 1;
    const int lg = l >> 4, lr_ = l & 15;
    const int xl0 = sl * 16 + lg * 4, kl = nilow * 16 + lr_;
    if (z < 32) {
        __shared__ unsigned char t8[32][33];   // [x][k]
        const int tx = tid & 31, ty = tid >> 5;
        #pragma unroll
        for (int r = ty; r < 32; r += 8)
            t8[r][tx] = (unsigned char)(i_att[((size_t)bh * 1024 + xt * 32 + r) * 256 + kt * 32 + tx] != 0);
        __syncthreads();
        #pragma unroll
        for (int r = ty; r < 32; r += 8)
            iattT8[((size_t)bh * 256 + kt * 32 + r) * 1024 + xt * 32 + tx] = t8[tx][r];
        ushort4 o;
        o.x = t8[xl0 + 0][kl] ? NEG : (u16)0;
        o.y = t8[xl0 + 1][kl] ? NEG : (u16)0;
        o.z = t8[xl0 + 2][kl] ? NEG : (u16)0;
        o.w = t8[xl0 + 3][kl] ? NEG : (u16)0;
        size_t eb = (((size_t)bh * 64 + xt * 2 + sl) * 8 + kt) * 512 + (size_t)l * 8 + nilow * 4;
        *reinterpret_cast<ushort4*>(iattBF + eb) = o;
    } else {
        const int kg = kt * 32 + kl;
        u16 o_[4];
        #pragma unroll
        for (int j = 0; j < 4; ++j) {
            int mm = cross[((size_t)bh * 1024 + xt * 32 + xl0 + j) * 256 + kg];
            o_[j] = mm ? NEG : (u16)0;
        }
        ushort4 o; o.x = o_[0]; o.y = o_[1]; o.z = o_[2]; o.w = o_[3];
        size_t eb = (((size_t)bh * 64 + xt * 2 + sl) * 8 + kt) * 512 + (size_t)l * 8 + nilow * 4;
        *reinterpret_cast<ushort4*>(crossBF + eb) = o;
    }
}

// ---------------------------------------------------------------------------
// main orientation: block per (b,k); reads polar row once, loops 8 heads.
// ---------------------------------------------------------------------------
__global__ __launch_bounds__(256) void main_ori_k8(
    const u16* __restrict__ S, const int* __restrict__ polar,
    int* __restrict__ MO)
{
    const int blk = blockIdx.x;          // b*256 + k
    const int b = blk >> 8, k = blk & 255;
    const int tid = threadIdx.x;
    const int wave = tid >> 6, lane = tid & 63;
    const int c = tid * 4;
    int4 p4 = *reinterpret_cast<const int4*>(polar + ((size_t)b * 256 + k) * 1024 + c);
    int pp[4] = { p4.x, p4.y, p4.z, p4.w };
    #pragma unroll
    for (int j = 0; j < 4; ++j) { int p = pp[j]; pp[j] = p < 0 ? 0 : (p > 7 ? 7 : p); }
    __shared__ float sred[4][8];
    for (int h = 0; h < 8; ++h) {
        const int bh = b * 8 + h;
        ushort4 sv = *reinterpret_cast<const ushort4*>(S + ((size_t)bh * 256 + k) * 1024 + c);
        float av[4] = { fabsf(b2f(sv.x)), fabsf(b2f(sv.y)), fabsf(b2f(sv.z)), fabsf(b2f(sv.w)) };
        float bins[8] = {};
        #pragma unroll
        for (int j = 0; j < 4; ++j) {
            #pragma unroll
            for (int o = 0; o < 8; ++o) bins[o] += (pp[j] == o) ? av[j] : 0.0f;
        }
        #pragma unroll
        for (int o = 0; o < 8; ++o) bins[o] = wred_sum(bins[o]);
        if (lane == 0) {
            #pragma unroll
            for (int o = 0; o < 8; ++o) sred[wave][o] = bins[o];
        }
        __syncthreads();
        if (tid == 0) {
            int best = 0; float bv = -1.0f;
            #pragma unroll
            for (int o = 0; o < 8; ++o) {
                float s = sred[0][o] + sred[1][o] + sred[2][o] + sred[3][o];
                if (s > bv) { bv = s; best = o; }
            }
            MO[bh * 256 + k] = best;
        }
        __syncthreads();
    }
}

// ---------------------------------------------------------------------------
// Combined bias build (after MO): biasF fragment order (-1e9) + bias1 [bh,k,x] (-1e6)
// ---------------------------------------------------------------------------
__global__ __launch_bounds__(256) void bias_build_k(
    const int* __restrict__ rd, const int* __restrict__ polar,
    const int* __restrict__ att, const float* __restrict__ dis,
    const float* __restrict__ pemb, const int* __restrict__ MO,
    u16* __restrict__ biasF, u16* __restrict__ bias1)
{
    const int b = blockIdx.z;
    const int xt = blockIdx.x * 32, kt = blockIdx.y * 32;
    const int tid = threadIdx.x;
    __shared__ float dsh[528];
    __shared__ int rds[32][33];   // [x][k]
    __shared__ int pls[32][33];
    __shared__ u16 bt[32][33];    // -1e6 variant [x][k]
    for (int i = tid; i < 528; i += 256) dsh[i] = dis[i];
    const int tx = tid & 31, ty = tid >> 5;
    #pragma unroll
    for (int r = ty; r < 32; r += 8) {
        size_t src = ((size_t)b * 256 + kt + r) * 1024 + xt + tx;  // rd[b,k,x]
        rds[tx][r] = rd[src];
        int p = polar[src]; pls[tx][r] = p < 0 ? 0 : (p > 7 ? 7 : p);
    }
    float pe[8];
    #pragma unroll
    for (int o = 0; o < 8; ++o) pe[o] = pemb[o];
    __syncthreads();
    const int sl = tid >> 7, rem = tid & 127, l = rem >> 1, nilow = rem & 1;
    const int lg = l >> 4, lr_ = l & 15;
    const int xl0 = sl * 16 + lg * 4, kl = nilow * 16 + lr_;
    const int kg = kt + kl;
    const u16 NEG9 = f2b(-1e9f), NEG6 = f2b(-1e6f);
    for (int h = 0; h < 8; ++h) {
        const int bh = b * 8 + h;
        int mo = MO[bh * 256 + kg];
        u16 o9[4];
        #pragma unroll
        for (int j = 0; j < 4; ++j) {
            int xl = xl0 + j;
            int mm = att[((size_t)bh * 1024 + xt + xl) * 256 + kg];
            float v = dsh[rds[xl][kl] * 8 + h] + pe[(pls[xl][kl] - mo + 8) & 7];
            u16 vb = f2b(v);
            o9[j] = mm ? NEG9 : vb;
            bt[xl][kl] = mm ? NEG6 : vb;
        }
        size_t eb = (((size_t)bh * 64 + (xt >> 4) + sl) * 8 + (kt >> 5)) * 512 + (size_t)l * 8 + nilow * 4;
        ushort4 ov; ov.x = o9[0]; ov.y = o9[1]; ov.z = o9[2]; ov.w = o9[3];
        *reinterpret_cast<ushort4*>(biasF + eb) = ov;
        __syncthreads();
        const int k_ = tid >> 3, x4 = (tid & 7) * 4;
        ushort4 o2;
        o2.x = bt[x4 + 0][k_]; o2.y = bt[x4 + 1][k_];
        o2.z = bt[x4 + 2][k_]; o2.w = bt[x4 + 3][k_];
        *reinterpret_cast<ushort4*>(bias1 + ((size_t)bh * 256 + kt + k_) * 1024 + xt + x4) = o2;
        __syncthreads();
    }
}

// ---------------------------------------------------------------------------
// Software-pipelined 128x128 staged MFMA core. AT = float (cast fused at
// staging) or u16. Optional A2 (bf16): summed into A at staging (runtime).
// ---------------------------------------------------------------------------
template<typename AT>
__device__ __forceinline__ void gemm_core_128(
    const AT* __restrict__ A, const AT* __restrict__ A2,
    const u16* __restrict__ Wt,
    int rb, int cb, short* Asl, short* Bsl, f32x4 (&acc)[4][4])
{
    constexpr bool F32 = sizeof(AT) == 4;
    const int tid = threadIdx.x;
    const int w = tid >> 6, lane = tid & 63;
    const int lr = lane & 15, lk = (lane >> 4) * 8;
    const int wr = (w >> 1) * 64, wc = (w & 1) * 64;
    const int srow = tid >> 3, skc = (tid & 7) * 8;
    const AT* gA = A + (size_t)(rb + srow) * 512 + skc;
    const AT* gA2 = A2 ? A2 + (size_t)(rb + srow) * 512 + skc : nullptr;
    const u16* gB = Wt + (size_t)(cb + srow) * 512 + skc;
    float4 ral[4], rah[4];
    bf16x8 rab[4], rab2[4], rw[4];
    #pragma unroll
    for (int it = 0; it < 4; ++it) {
        if constexpr (F32) {
            ral[it] = *reinterpret_cast<const float4*>(gA + (size_t)it * 32 * 512);
            rah[it] = *reinterpret_cast<const float4*>(gA + (size_t)it * 32 * 512 + 4);
        } else {
            rab[it] = *reinterpret_cast<const bf16x8*>(gA + (size_t)it * 32 * 512);
            if (gA2) rab2[it] = *reinterpret_cast<const bf16x8*>(gA2 + (size_t)it * 32 * 512);
        }
        rw[it] = *reinterpret_cast<const bf16x8*>(gB + (size_t)it * 32 * 512);
    }
    for (int t = 0; t < 8; ++t) {
        #pragma unroll
        for (int it = 0; it < 4; ++it) {
            if constexpr (F32) {
                u16x8 o;
                o[0] = f2b(ral[it].x); o[1] = f2b(ral[it].y);
                o[2] = f2b(ral[it].z); o[3] = f2b(ral[it].w);
                o[4] = f2b(rah[it].x); o[5] = f2b(rah[it].y);
                o[6] = f2b(rah[it].z); o[7] = f2b(rah[it].w);
                *reinterpret_cast<u16x8*>(&Asl[(it * 32 + srow) * 72 + skc]) = o;
            } else {
                if (gA2) {
                    u16x8 o;
                    #pragma unroll
                    for (int e = 0; e < 8; ++e)
                        o[e] = f2b(b2f((u16)rab[it][e]) + b2f((u16)rab2[it][e]));
                    *reinterpret_cast<u16x8*>(&Asl[(it * 32 + srow) * 72 + skc]) = o;
                } else {
                    *reinterpret_cast<bf16x8*>(&Asl[(it * 32 + srow) * 72 + skc]) = rab[it];
                }
            }
            *reinterpret_cast<bf16x8*>(&Bsl[(it * 32 + srow) * 72 + skc]) = rw[it];
        }
        if (t < 7) {
            const int k0 = (t + 1) * 64;
            #pragma unroll
            for (int it = 0; it < 4; ++it) {
                if constexpr (F32) {
                    ral[it] = *reinterpret_cast<const float4*>(gA + k0 + (size_t)it * 32 * 512);
                    rah[it] = *reinterpret_cast<const float4*>(gA + k0 + (size_t)it * 32 * 512 + 4);
                } else {
                    rab[it] = *reinterpret_cast<const bf16x8*>(gA + k0 + (size_t)it * 32 * 512);
                    if (gA2) rab2[it] = *reinterpret_cast<const bf16x8*>(gA2 + k0 + (size_t)it * 32 * 512);
                }
                rw[it] = *reinterpret_cast<const bf16x8*>(gB + k0 + (size_t)it * 32 * 512);
            }
        }
        __syncthreads();
        #pragma unroll
        for (int ks = 0; ks < 2; ++ks) {
            bf16x8 af[4], bf_[4];
            #pragma unroll
            for (int mi = 0; mi < 4; ++mi)
                af[mi] = *reinterpret_cast<const bf16x8*>(&Asl[(wr + mi * 16 + lr) * 72 + ks * 32 + lk]);
            #pragma unroll
            for (int ni = 0; ni < 4; ++ni)
                bf_[ni] = *reinterpret_cast<const bf16x8*>(&Bsl[(wc + ni * 16 + lr) * 72 + ks * 32 + lk]);
            #pragma unroll
            for (int mi = 0; mi < 4; ++mi)
                #pragma unroll
                for (int ni = 0; ni < 4; ++ni)
                    acc[mi][ni] = mfma16(af[mi], bf_[ni], acc[mi][ni]);
        }
        __syncthreads();
    }
}

// ---------------------------------------------------------------------------
// QKV GEMM body with coalesced epilogues. q/k: restage via LDS [128][136],
// then 8 lanes cover a 128B row run (full cachelines). v: LDS transpose then
// 8-threads-per-row 16B writes.
// ---------------------------------------------------------------------------
template<typename AT>
__device__ __forceinline__ void qkv_body(
    const AT* __restrict__ A, const u16* __restrict__ Wt,
    u16* __restrict__ qb, u16* __restrict__ kb, u16* __restrict__ vt,
    int sl, int rb, int cb)
{
    __shared__ __align__(16) short Ls[2 * 128 * 72];
    short* Asl = Ls;
    short* Bsl = Ls + 128 * 72;
    f32x4 acc[4][4] = {};
    gemm_core_128<AT>(A, nullptr, Wt, rb, cb, Asl, Bsl, acc);
    const int tid = threadIdx.x;
    const int wave = tid >> 6, lane = tid & 63;
    const int lr = lane & 15, lg = lane >> 4;
    const int wr = (wave >> 1) * 64, wc = (wave & 1) * 64;
    const int seq = 1 << sl, smask = seq - 1;
    if (cb < 1024) {
        const float scl = (cb < 512) ? 0.125f : 1.0f;
        #pragma unroll
        for (int mi = 0; mi < 4; ++mi)
            #pragma unroll
            for (int ni = 0; ni < 4; ++ni) {
                int row = wr + mi * 16 + lg * 4;
                int col = wc + ni * 16 + lr;
                f32x4 v = acc[mi][ni];
                #pragma unroll
                for (int j = 0; j < 4; ++j)
                    Ls[(row + j) * 136 + col] = (short)f2b(v[j] * scl);
            }
        __syncthreads();
        u16* dst = (cb < 512) ? qb : kb;
        if (dst) {
            const int cbase = (cb < 512) ? cb : cb - 512;
            #pragma unroll
            for (int p = 0; p < 8; ++p) {
                int slot = p * 256 + tid;
                int row = slot >> 4;
                int half = (slot >> 3) & 1;
                int inner = slot & 7;
                int m = rb + row;
                int bb = m >> sl, n = m & smask;
                int cg = cbase + half * 64;
                int h = cg >> 6;
                u16x8 val = *reinterpret_cast<u16x8*>(&Ls[row * 136 + half * 64 + inner * 8]);
                *reinterpret_cast<u16x8*>(
                    &dst[(((size_t)bb * HH + h) * seq + n) * 64 + inner * 8]) = val;
            }
        }
    } else {
        #pragma unroll
        for (int mi = 0; mi < 4; ++mi)
            #pragma unroll
            for (int ni = 0; ni < 4; ++ni) {
                int col = wc + ni * 16 + lr;
                int row0 = wr + mi * 16 + lg * 4;
                f32x4 v = acc[mi][ni];
                #pragma unroll
                for (int j = 0; j < 4; ++j)
                    Ls[col * 136 + row0 + j] = (short)f2b(v[j]);
            }
        __syncthreads();
        const int bb = rb >> sl, n0 = rb & smask;
        #pragma unroll
        for (int p = 0; p < 4; ++p) {
            int slot = p * 256 + tid;
            int col = slot >> 3;
            int inner = slot & 7;
            int dg = (cb - 1024) + col;
            int h = dg >> 6, d = dg & 63;
            u16* vrow = vt + ((((size_t)bb * HH + h) * 64 + d) << sl) + n0;
            u16x8 v0 = *reinterpret_cast<u16x8*>(&Ls[col * 136 + inner * 8]);
            u16x8 v1 = *reinterpret_cast<u16x8*>(&Ls[col * 136 + 64 + inner * 8]);
            *reinterpret_cast<u16x8*>(vrow + inner * 8) = v0;
            *reinterpret_cast<u16x8*>(vrow + 64 + inner * 8) = v1;
        }
    }
}

// All 4 first-stage QKV GEMMs (f32 input, cast fused): 960 blocks, XCD swizzle
__global__ __launch_bounds__(256, 3) void gemm_qkv_all_k(
    const float* __restrict__ A0, const float* __restrict__ A1,
    const float* __restrict__ A2, const float* __restrict__ A3,
    const u16* __restrict__ W01, const u16* __restrict__ W23,
    u16* q0, u16* k0, u16* v0, u16* q1, u16* k1, u16* v1,
    u16* q2, u16* k2, u16* v2, u16* q3, u16* k3, u16* v3)
{
    const int lin = blockIdx.x;
    const int swz = (lin & 7) * 120 + (lin >> 3);
    const int x = swz % 12, y = swz / 12;
    const float* A; const u16* Wt; u16 *qb, *kb, *vt; int sl, ry;
    if (y < 32)      { A = A0; Wt = W01; qb = q0; kb = k0; vt = v0; sl = 10; ry = y; }
    else if (y < 40) { A = A1; Wt = W01; qb = q1; kb = k1; vt = v1; sl = 8;  ry = y - 32; }
    else if (y < 72) { A = A2; Wt = W23; qb = q2; kb = k2; vt = v2; sl = 10; ry = y - 40; }
    else             { A = A3; Wt = W23; qb = q3; kb = k3; vt = v3; sl = 8;  ry = y - 72; }
    qkv_body<float>(A, Wt, qb, kb, vt, sl, ry * 128, x * 128);
}

// Second-stage QKV GEMM (IKOUT, bf16 input): only k/v columns (x offset +4)
__global__ __launch_bounds__(256, 3) void gemm_qkv2_k(
    const u16* __restrict__ A, const u16* __restrict__ Wt,
    u16* kb, u16* vt)
{
    qkv_body<u16>(A, Wt, nullptr, kb, vt, 8, blockIdx.y * 128, (blockIdx.x + 4) * 128);
}

// ---------------------------------------------------------------------------
// Proj GEMM body (pipelined core, bf16 A, optional A2 summed) + bias epilogue
// ---------------------------------------------------------------------------
template<bool OUTBF>
__device__ __forceinline__ void proj_body(
    const u16* __restrict__ A, const u16* __restrict__ A2,
    const u16* __restrict__ Wt,
    const float* __restrict__ bias, float bscale, void* __restrict__ outp,
    int rb, int cb)
{
    __shared__ __align__(16) short Ls[2 * 128 * 72];
    f32x4 acc[4][4] = {};
    gemm_core_128<u16>(A, A2, Wt, rb, cb, Ls, Ls + 128 * 72, acc);
    const int tid = threadIdx.x;
    const int wave = tid >> 6, lane = tid & 63;
    const int lr = lane & 15;
    const int wr = (wave >> 1) * 64, wc = (wave & 1) * 64;
    #pragma unroll
    for (int mi = 0; mi < 4; ++mi) {
        int m0 = rb + wr + mi * 16 + (lane >> 4) * 4;
        #pragma unroll
        for (int ni = 0; ni < 4; ++ni) {
            int c = cb + wc + ni * 16 + lr;
            float bv = bscale * bias[c];
            f32x4 v = acc[mi][ni];
            #pragma unroll
            for (int j = 0; j < 4; ++j) {
                size_t o = (size_t)(m0 + j) * 512 + c;
                if (OUTBF) reinterpret_cast<u16*>(outp)[o] = f2b(v[j] + bv);
                else       reinterpret_cast<float*>(outp)[o] = v[j] + bv;
            }
        }
    }
}

// single proj (IKOUT, bf16 out)
__global__ __launch_bounds__(256, 3) void gemm_proj_bf16_k(
    const u16* __restrict__ A, const u16* __restrict__ Wt,
    const float* __restrict__ bias, float bscale, u16* __restrict__ outp)
{
    proj_body<true>(A, nullptr, Wt, bias, bscale, outp, blockIdx.y * 128, blockIdx.x * 128);
}

// final combined proj: 288 linear blocks (128 x_out [dual-A], 128 i_x_out, 32 k_out)
__global__ __launch_bounds__(256, 3) void gemm_proj3_k(
    const u16* __restrict__ A0, const u16* __restrict__ A0b,
    const u16* __restrict__ A1, const u16* __restrict__ A2,
    const u16* __restrict__ W, const u16* __restrict__ Wi2,
    const float* __restrict__ bp, const float* __restrict__ bpi2,
    float* __restrict__ o0, float* __restrict__ o1, float* __restrict__ o2)
{
    const int id = blockIdx.x;
    const u16 *A, *Ax; const u16* Wt; const float* bias; float bscale; float* outp; int x, y;
    if (id < 128)      { A = A0; Ax = A0b; Wt = W;   bias = bp;   bscale = 2.0f; outp = o0; x = id & 3; y = id >> 2; }
    else if (id < 256) { A = A1; Ax = nullptr; Wt = Wi2; bias = bpi2; bscale = 1.0f; outp = o1; x = (id - 128) & 3; y = (id - 128) >> 2; }
    else               { A = A2; Ax = nullptr; Wt = W;   bias = bp;   bscale = 1.0f; outp = o2; x = (id - 256) & 3; y = (id - 256) >> 2; }
    proj_body<false>(A, Ax, Wt, bias, bscale, outp, y * 128, x * 128);
}

// ---------------------------------------------------------------------------
// Paired wide scores with coalesced S epilogue via LDS restage.
// z<32 -> (KQ,KX)->SPa ; else (IKQ,IK)->SPb. R=256,C=1024.
// ---------------------------------------------------------------------------
__global__ __launch_bounds__(256, 4) void scores_pair_k(
    const u16* __restrict__ A1, const u16* __restrict__ B1, u16* __restrict__ S1,
    const u16* __restrict__ A2, const u16* __restrict__ B2, u16* __restrict__ S2)
{
    __shared__ __align__(16) short Ls[2 * 128 * 72];
    short* As = Ls;
    short* Bs = Ls + 128 * 72;
    const int z = blockIdx.z, bh = z & 31;
    const u16* Aq = (z < 32) ? A1 : A2;
    const u16* Bk = (z < 32) ? B1 : B2;
    u16* S = (z < 32) ? S1 : S2;
    const int tid = threadIdx.x;
    const int wave = tid >> 6, lane = tid & 63;
    const int lr = lane & 15, lg = lane >> 4, lk = lg * 8;
    const int rb = blockIdx.y * 128, cb = blockIdx.x * 128;
    const int wr = (wave >> 1) * 64, wc = (wave & 1) * 64;
    const u16* Ap = Aq + (size_t)bh * 256 * 64;
    const u16* Bp = Bk + (size_t)bh * 1024 * 64;
    const int srow = tid >> 3, skc = (tid & 7) * 8;
    #pragma unroll
    for (int it = 0; it < 4; ++it) {
        int row = it * 32 + srow;
        *reinterpret_cast<bf16x8*>(&As[row * 72 + skc]) =
            *reinterpret_cast<const bf16x8*>(Ap + (size_t)(rb + row) * 64 + skc);
        *reinterpret_cast<bf16x8*>(&Bs[row * 72 + skc]) =
            *reinterpret_cast<const bf16x8*>(Bp + (size_t)(cb + row) * 64 + skc);
    }
    __syncthreads();
    f32x4 acc[4][4] = {};
    #pragma unroll
    for (int ks = 0; ks < 2; ++ks) {
        bf16x8 af[4], bf_[4];
        #pragma unroll
        for (int mi = 0; mi < 4; ++mi)
            af[mi] = *reinterpret_cast<const bf16x8*>(&As[(wr + mi * 16 + lr) * 72 + ks * 32 + lk]);
        #pragma unroll
        for (int ni = 0; ni < 4; ++ni)
            bf_[ni] = *reinterpret_cast<const bf16x8*>(&Bs[(wc + ni * 16 + lr) * 72 + ks * 32 + lk]);
        #pragma unroll
        for (int mi = 0; mi < 4; ++mi)
            #pragma unroll
            for (int ni = 0; ni < 4; ++ni)
                acc[mi][ni] = mfma16(af[mi], bf_[ni], acc[mi][ni]);
    }
    __syncthreads();   // all LDS reads done -> reuse Ls as [128][136] epilogue buffer
    #pragma unroll
    for (int mi = 0; mi < 4; ++mi)
        #pragma unroll
        for (int ni = 0; ni < 4; ++ni) {
            int row = wr + mi * 16 + lg * 4;
            int col = wc + ni * 16 + lr;
            f32x4 v = acc[mi][ni];
            #pragma unroll
            for (int j = 0; j < 4; ++j)
                Ls[(row + j) * 136 + col] = (short)f2b(v[j]);
        }
    __syncthreads();
    #pragma unroll
    for (int p = 0; p < 8; ++p) {
        int slot = p * 256 + tid;
        int row = slot >> 4;
        int chunk = slot & 15;
        u16x8 val = *reinterpret_cast<u16x8*>(&Ls[row * 136 + chunk * 8]);
        *reinterpret_cast<u16x8*>(
            &S[((size_t)bh * 256 + rb + row) * 1024 + cb + chunk * 8]) = val;
    }
}

// ---------------------------------------------------------------------------
// Paired wide softmax: rows [0,8192) -> SPa + bf16 bias1 ; [8192,16384) ->
// SPb + u8 maskT (-1e9).
// ---------------------------------------------------------------------------
__global__ __launch_bounds__(256) void softmax_pair_k(
    u16* __restrict__ S1, const u16* __restrict__ bias1,
    u16* __restrict__ S2, const unsigned char* __restrict__ maskT)
{
    const int rg = blockIdx.x;
    const bool first = rg < 8192;
    const int row_g = first ? rg : rg - 8192;
    const int tid = threadIdx.x;
    const int wave = tid >> 6, lane = tid & 63;
    const int c = tid * 4;
    u16* rowp = (first ? S1 : S2) + (size_t)row_g * 1024;
    ushort4 sv = *reinterpret_cast<const ushort4*>(rowp + c);
    float s[4] = { b2f(sv.x), b2f(sv.y), b2f(sv.z), b2f(sv.w) };
    if (first) {
        ushort4 bv = *reinterpret_cast<const ushort4*>(bias1 + (size_t)row_g * 1024 + c);
        s[0] += b2f(bv.x); s[1] += b2f(bv.y); s[2] += b2f(bv.z); s[3] += b2f(bv.w);
    } else {
        uchar4 mk = *reinterpret_cast<const uchar4*>(maskT + (size_t)row_g * 1024 + c);
        if (mk.x) s[0] = -1e9f; if (mk.y) s[1] = -1e9f;
        if (mk.z) s[2] = -1e9f; if (mk.w) s[3] = -1e9f;
    }
    __shared__ float swv[4];
    float lm = fmaxf(fmaxf(s[0], s[1]), fmaxf(s[2], s[3]));
    lm = wred_max(lm);
    if (lane == 0) swv[wave] = lm;
    __syncthreads();
    float m = fmaxf(fmaxf(swv[0], swv[1]), fmaxf(swv[2], swv[3]));
    __syncthreads();
    float ls = 0.0f;
    #pragma unroll
    for (int j = 0; j < 4; ++j) { s[j] = __expf(s[j] - m); ls += s[j]; }
    ls = wred_sum(ls);
    if (lane == 0) swv[wave] = ls;
    __syncthreads();
    float inv = 1.0f / (swv[0] + swv[1] + swv[2] + swv[3]);
    ushort4 ov = { f2b(s[0] * inv), f2b(s[1] * inv), f2b(s[2] * inv), f2b(s[3] * inv) };
    *reinterpret_cast<ushort4*>(rowp + c) = ov;
}

// ---------------------------------------------------------------------------
// Paired PV with coalesced per-wave epilogue. z=0: (SPa,VXt)->KMb ;
// z=1: (SPb,IVt)->KMb2
// ---------------------------------------------------------------------------
__global__ __launch_bounds__(256, 4) void pv_pair_k(
    const u16* __restrict__ P1, const u16* __restrict__ V1, u16* __restrict__ o1,
    const u16* __restrict__ P2, const u16* __restrict__ V2, u16* __restrict__ o2)
{
    __shared__ __align__(16) short Ps[4 * 16 * 72];
    const int z = blockIdx.z;
    const u16* P = z ? P2 : P1;
    const u16* V = z ? V2 : V1;
    u16* out = z ? o2 : o1;
    const int tid = threadIdx.x;
    const int wave = tid >> 6, lane = tid & 63;
    const int lr = lane & 15, lg = lane >> 4, lk = lg * 8;
    const int bh = blockIdx.y, b = bh >> 3, h = bh & 7;
    const int rb = blockIdx.x * 64;
    const int wr = wave * 16;
    f32x4 acc[4] = {};
    const u16* Pb = P + ((size_t)bh * 256 + rb) * 1024;
    const u16* Vb = V + (size_t)bh * 64 * 1024;
    for (int c0 = 0; c0 < 1024; c0 += 64) {
        #pragma unroll
        for (int ks = 0; ks < 2; ++ks) {
            bf16x8 ap = *reinterpret_cast<const bf16x8*>(
                Pb + (size_t)(wr + lr) * 1024 + c0 + ks * 32 + lk);
            #pragma unroll
            for (int ni = 0; ni < 4; ++ni) {
                bf16x8 vv = *reinterpret_cast<const bf16x8*>(
                    Vb + (size_t)(ni * 16 + lr) * 1024 + c0 + ks * 32 + lk);
                acc[ni] = mfma16(ap, vv, acc[ni]);
            }
        }
    }
    short* myP = &Ps[wave * 16 * 72];
    #pragma unroll
    for (int ni = 0; ni < 4; ++ni) {
        int d = ni * 16 + lr;
        f32x4 v = acc[ni];
        #pragma unroll
        for (int j = 0; j < 4; ++j)
            myP[(lg * 4 + j) * 72 + d] = (short)f2b(v[j]);
    }
    #pragma unroll
    for (int p = 0; p < 2; ++p) {
        int slot = p * 64 + lane;
        int rloc = slot >> 3;
        int inner = slot & 7;
        int r0 = rb + wr + rloc;
        u16x8 val = *reinterpret_cast<u16x8*>(&myP[rloc * 72 + inner * 8]);
        *reinterpret_cast<u16x8*>(
            &out[((size_t)(b * 256 + r0)) * 512 + h * 64 + inner * 8]) = val;
    }
}

// ---------------------------------------------------------------------------
// Merged fused attention: 1536 blocks.
//  [0,512)    : branch2 src0 (Q, KK, KVt, biasF)   -> XMb
//  [512,1024) : branch2 src1 (Q, IKK, IKVt, crossBF)-> XMc
//  [1024,1536): branch3     (IQ, K2K, K2Vt, iattBF) -> XMb2
// 64 x-rows/block, 4 waves, wave owns 16 rows, zero barriers.
// ---------------------------------------------------------------------------
__global__ __launch_bounds__(256, 4) void attn_all_k(
    const u16* __restrict__ Q0, const u16* __restrict__ IQ0,
    const u16* __restrict__ K1, const u16* __restrict__ V1t,
    const u16* __restrict__ B1F, u16* __restrict__ out1,
    const u16* __restrict__ K2, const u16* __restrict__ V2t,
    const u16* __restrict__ B2F, u16* __restrict__ out2,
    const u16* __restrict__ K3, const u16* __restrict__ V3t,
    const u16* __restrict__ B3F, u16* __restrict__ out3)
{
    const int tid = threadIdx.x;
    const int w = tid >> 6, lane = tid & 63;
    const int lr = lane & 15, lg = lane >> 4, lk = lg * 8;
    int lin = blockIdx.x;
    const u16 *Qp, *Kp, *Vp, *BF; u16* outm;
    if (lin < 512)        { Qp = Q0;  Kp = K1; Vp = V1t; BF = B1F; outm = out1; }
    else if (lin < 1024)  { Qp = Q0;  Kp = K2; Vp = V2t; BF = B2F; outm = out2; lin -= 512; }
    else                  { Qp = IQ0; Kp = K3; Vp = V3t; BF = B3F; outm = out3; lin -= 1024; }
    const int xcd = lin & 7, idx = lin >> 3;
    const int bh = xcd * 4 + (idx & 3);
    const int rb = (idx >> 2) * 64;
    const int b = bh >> 3, h = bh & 7;
    const int wr = w * 16;
    const int strip = (rb >> 4) + w;

    __shared__ __align__(16) short Ps[4 * 16 * 264];   // per-wave scratch
    short* myP = &Ps[w * 16 * 264];

    bf16x8 qf0, qf1;
    {
        const u16* Qb = Qp + ((size_t)bh * 1024 + rb + wr + lr) * 64;
        qf0 = *reinterpret_cast<const bf16x8*>(Qb + lk);
        qf1 = *reinterpret_cast<const bf16x8*>(Qb + 32 + lk);
    }

    // bias prefetch (fragment order): 8 x 16B fully-coalesced loads
    bf16x8 breg[8];
    {
        const u16* bb = BF + (((size_t)bh * 64 + strip) * 8) * 512 + (size_t)lane * 8;
        #pragma unroll
        for (int itp = 0; itp < 8; ++itp)
            breg[itp] = *reinterpret_cast<const bf16x8*>(bb + (size_t)itp * 512);
    }
    // scores: 16 rows x 256 cols per wave; K direct from global (L2)
    const u16* Kb = Kp + (size_t)bh * 256 * 64;
    f32x4 acc[16];
    #pragma unroll
    for (int ni = 0; ni < 16; ++ni) acc[ni] = (f32x4){0.f, 0.f, 0.f, 0.f};
    #pragma unroll
    for (int ni = 0; ni < 16; ++ni) {
        bf16x8 b0 = *reinterpret_cast<const bf16x8*>(Kb + (size_t)(ni * 16 + lr) * 64 + lk);
        acc[ni] = mfma16(qf0, b0, acc[ni]);
    }
    #pragma unroll
    for (int ni = 0; ni < 16; ++ni) {
        bf16x8 b1 = *reinterpret_cast<const bf16x8*>(Kb + (size_t)(ni * 16 + lr) * 64 + 32 + lk);
        acc[ni] = mfma16(qf1, b1, acc[ni]);
    }
    // bias from regs + in-wave softmax
    float mx[4] = { -3.4e38f, -3.4e38f, -3.4e38f, -3.4e38f };
    #pragma unroll
    for (int ni = 0; ni < 16; ++ni) {
        const bf16x8 br = breg[ni >> 1];
        #pragma unroll
        for (int j = 0; j < 4; ++j) {
            float v = acc[ni][j] + b2f((u16)br[(ni & 1) * 4 + j]);
            acc[ni][j] = v;
            mx[j] = fmaxf(mx[j], v);
        }
    }
    #pragma unroll
    for (int j = 0; j < 4; ++j) {
        #pragma unroll
        for (int o = 1; o < 16; o <<= 1) mx[j] = fmaxf(mx[j], __shfl_xor(mx[j], o, 64));
    }
    float sm[4] = {};
    #pragma unroll
    for (int ni = 0; ni < 16; ++ni) {
        #pragma unroll
        for (int j = 0; j < 4; ++j) {
            float e = __expf(acc[ni][j] - mx[j]);
            acc[ni][j] = e;
            sm[j] += e;
        }
    }
    #pragma unroll
    for (int j = 0; j < 4; ++j) {
        #pragma unroll
        for (int o = 1; o < 16; o <<= 1) sm[j] += __shfl_xor(sm[j], o, 64);
        sm[j] = 1.0f / sm[j];
    }
    // P to wave-local LDS (in-wave transpose), then PV with V from global
    #pragma unroll
    for (int ni = 0; ni < 16; ++ni)
        #pragma unroll
        for (int j = 0; j < 4; ++j)
            myP[(lg * 4 + j) * 264 + ni * 16 + lr] = (short)f2b(acc[ni][j] * sm[j]);
    f32x4 acc2[4] = {};
    #pragma unroll
    for (int kc = 0; kc < 8; ++kc) {
        bf16x8 ap = *reinterpret_cast<const bf16x8*>(&myP[lr * 264 + kc * 32 + lk]);
        #pragma unroll
        for (int ni = 0; ni < 4; ++ni) {
            bf16x8 vv = *reinterpret_cast<const bf16x8*>(
                Vp + ((size_t)bh * 64 + ni * 16 + lr) * 256 + kc * 32 + lk);
            acc2[ni] = mfma16(ap, vv, acc2[ni]);
        }
    }
    // coalesced epilogue: restage 16x64 tile (stride 72), 8 lanes per 128B row
    #pragma unroll
    for (int ni = 0; ni < 4; ++ni) {
        int d = ni * 16 + lr;
        f32x4 v = acc2[ni];
        #pragma unroll
        for (int j = 0; j < 4; ++j)
            myP[(lg * 4 + j) * 72 + d] = (short)f2b(v[j]);
    }
    #pragma unroll
    for (int p = 0; p < 2; ++p) {
        int slot = p * 64 + lane;
        int rloc = slot >> 3;
        int inner = slot & 7;
        int row = rb + wr + rloc;
        u16x8 val = *reinterpret_cast<u16x8*>(&myP[rloc * 72 + inner * 8]);
        *reinterpret_cast<u16x8*>(
            &outm[((size_t)(b * 1024 + row)) * 512 + h * 64 + inner * 8]) = val;
    }
}

// ---------------------------------------------------------------------------
extern "C" void kernel_launch(void* const* d_in, const int* in_sizes, int n_in,
                              void* d_out, int out_size, void* d_ws, size_t ws_size,
                              hipStream_t stream)
{
    const float* x        = (const float*)d_in[0];
    const float* kernal   = (const float*)d_in[1];
    const float* i_x      = (const float*)d_in[2];
    const float* i_kernal = (const float*)d_in[3];
    const int*   rd       = (const int*)d_in[4];
    const int*   polar    = (const int*)d_in[5];
    const int*   att      = (const int*)d_in[6];
    const int*   i_att    = (const int*)d_in[7];
    const int*   cross    = (const int*)d_in[8];
    const float* Wqkv     = (const float*)d_in[9];
    const float* Wqkv_i   = (const float*)d_in[10];
    const float* Wqkv_i2  = (const float*)d_in[11];
    const float* Wproj    = (const float*)d_in[12];
    const float* bproj    = (const float*)d_in[13];
    const float* Wproj_i  = (const float*)d_in[14];
    const float* bproj_i  = (const float*)d_in[15];
    const float* Wproj_i2 = (const float*)d_in[16];
    const float* bproj_i2 = (const float*)d_in[17];
    const float* dis      = (const float*)d_in[18];
    const float* pemb     = (const float*)d_in[19];

    float* out = (float*)d_out;
    float* x_out   = out;
    float* k_out   = out + (size_t)BB * XLL * DIMM;
    float* i_x_out = k_out + (size_t)BB * KLL * DIMM;

    char* ws = (char*)d_ws;
    size_t off = 0;
    auto alloc = [&](size_t bytes) { void* p = ws + off; off += (bytes + 255) & ~(size_t)255; return p; };

    const size_t NAX = (size_t)BB * XLL * DIMM;
    const size_t NAK = (size_t)BB * KLL * DIMM;
    const size_t NHX = (size_t)BHH * XLL * HEADD;
    const size_t NHK = (size_t)BHH * KLL * HEADD;
    const size_t NS  = (size_t)BHH * KLL * XLL;

    u16* WqkvT    = (u16*)alloc((size_t)1536 * 512 * 2);
    u16* WqkvIT   = (u16*)alloc((size_t)1536 * 512 * 2);
    u16* WqkvI2T  = (u16*)alloc((size_t)1536 * 512 * 2);
    u16* WprojT   = (u16*)alloc((size_t)512 * 512 * 2);
    u16* WprojIT  = (u16*)alloc((size_t)512 * 512 * 2);
    u16* WprojI2T = (u16*)alloc((size_t)512 * 512 * 2);
    u16* Q    = (u16*)alloc(NHX * 2);
    u16* KX   = (u16*)alloc(NHX * 2);
    u16* VXt  = (u16*)alloc(NHX * 2);
    u16* IQ   = (u16*)alloc(NHX * 2);
    u16* IK   = (u16*)alloc(NHX * 2);
    u16* IVt  = (u16*)alloc(NHX * 2);
    u16* KQ   = (u16*)alloc(NHK * 2);
    u16* KK   = (u16*)alloc(NHK * 2);
    u16* KVt  = (u16*)alloc(NHK * 2);
    u16* IKQ  = (u16*)alloc(NHK * 2);
    u16* IKK  = (u16*)alloc(NHK * 2);
    u16* IKVt = (u16*)alloc(NHK * 2);
    u16* K2K  = (u16*)alloc(NHK * 2);
    u16* K2Vt = (u16*)alloc(NHK * 2);
    u16* SPa  = (u16*)alloc(NS * 2);
    u16* SPb  = (u16*)alloc(NS * 2);
    u16* KMb  = (u16*)alloc(NAK * 2);
    u16* KMb2 = (u16*)alloc(NAK * 2);
    u16* XMb  = (u16*)alloc(NAX * 2);
    u16* XMb2 = (u16*)alloc(NAX * 2);
    u16* XMc  = (u16*)alloc(NAX * 2);
    u16* IKOUTb = (u16*)alloc(NAK * 2);
    u16* biasF = (u16*)alloc(NS * 2);
    u16* bias1 = (u16*)alloc(NS * 2);
    u16* crossBF = (u16*)alloc(NS * 2);
    u16* iattBF  = (u16*)alloc(NS * 2);
    unsigned char* iattT8 = (unsigned char*)alloc(NS);
    int* MO   = (int*)alloc((size_t)BHH * KLL * 4);

    dim3 blk(256);

    // 1. merged prep (weight transposes + mask conversions)
    prep_all_k<<<dim3(19456), blk, 0, stream>>>(
        Wqkv, Wqkv_i, Wqkv_i2, Wproj, Wproj_i, Wproj_i2,
        WqkvT, WqkvIT, WqkvI2T, WprojT, WprojIT, WprojI2T,
        i_att, iattT8, iattBF, cross, crossBF);

    // 2. all first-stage QKV GEMMs (cast fused, q pre-scaled), XCD-swizzled
    gemm_qkv_all_k<<<dim3(960), blk, 0, stream>>>(
        x, kernal, i_x, i_kernal, WqkvT, WqkvIT,
        Q, KX, VXt, KQ, KK, KVt, IQ, IK, IVt, IKQ, IKK, IKVt);

    // 3. wide scores (branch1 + branch3)
    scores_pair_k<<<dim3(8, 2, 64), blk, 0, stream>>>(KQ, KX, SPa, IKQ, IK, SPb);
    // 4. main orientation + bias builds
    main_ori_k8<<<dim3(BB * KLL), blk, 0, stream>>>(SPa, polar, MO);
    bias_build_k<<<dim3(32, 8, BB), blk, 0, stream>>>(rd, polar, att, dis, pemb, MO, biasF, bias1);
    // 5. wide softmaxes
    softmax_pair_k<<<dim3(16384), blk, 0, stream>>>(SPa, bias1, SPb, iattT8);
    // 6. wide PVs (barrier-free)
    pv_pair_k<<<dim3(4, 32, 2), blk, 0, stream>>>(SPa, VXt, KMb, SPb, IVt, KMb2);
    // 7. IKOUT proj (bf16) + second qkv (k/v columns only)
    gemm_proj_bf16_k<<<dim3(4, 8), blk, 0, stream>>>(KMb2, WprojIT, bproj_i, 1.0f, IKOUTb);
    gemm_qkv2_k<<<dim3(8, 8), blk, 0, stream>>>(IKOUTb, WqkvI2T, K2K, K2Vt);
    // 8. all three fused attentions in one launch (1536 blocks)
    attn_all_k<<<dim3(1536), blk, 0, stream>>>(
        Q, IQ, KK, KVt, biasF, XMb, IKK, IKVt, crossBF, XMc,
        K2K, K2Vt, iattBF, XMb2);
    // 9. final combined projections (x_out = (XMb+XMc)@W, i_x_out, k_out)
    gemm_proj3_k<<<dim3(288), blk, 0, stream>>>(
        XMb, XMc, XMb2, KMb, WprojT, WprojI2T, bproj, bproj_i2, x_out, i_x_out, k_out);

    (void)in_sizes; (void)n_in; (void)out_size; (void)ws_size;
}

// Round 21
// 249.813 us; speedup vs baseline: 1.1619x; 1.0293x over previous
//
#include <hip/hip_runtime.h>
#include <cstddef>
#include <cstdint>

#define BB 4
#define HH 8
#define HEADD 64
#define DIMM 512
#define XLL 1024
#define KLL 256
#define BHH (BB*HH)

typedef __attribute__((ext_vector_type(8))) short bf16x8;
typedef __attribute__((ext_vector_type(8))) unsigned short u16x8;
typedef __attribute__((ext_vector_type(4))) float f32x4;
typedef unsigned short u16;
typedef unsigned long long u64;

__device__ __forceinline__ u16 f2b(float f) {
    unsigned int u = __builtin_bit_cast(unsigned int, f);
    u = u + 0x7fffu + ((u >> 16) & 1u);
    return (u16)(u >> 16);
}
__device__ __forceinline__ float b2f(u16 h) {
    unsigned int u = ((unsigned int)h) << 16;
    return __builtin_bit_cast(float, u);
}
__device__ __forceinline__ f32x4 mfma16(bf16x8 a, bf16x8 b, f32x4 c) {
    return __builtin_amdgcn_mfma_f32_16x16x32_bf16(a, b, c, 0, 0, 0);
}
__device__ __forceinline__ float wred_max(float v) {
    #pragma unroll
    for (int o = 1; o < 64; o <<= 1) v = fmaxf(v, __shfl_xor(v, o, 64));
    return v;
}
__device__ __forceinline__ float wred_sum(float v) {
    #pragma unroll
    for (int o = 1; o < 64; o <<= 1) v += __shfl_xor(v, o, 64);
    return v;
}

// Fragment-order bias layout:
//   E(bh,x,k) = ((bh*64 + (x>>4))*8 + (k>>5))*512
//             + (((x>>2)&3)*16 + (k&15))*8 + ((k>>4)&1)*4 + (x&3)

// ---------------------------------------------------------------------------
// Merged prep: blocks [0,3072) = 6 weight transposes (f32 [K][N]->bf16 [N][K]);
// blocks [3072,19456) = mask prep (i_att -> iattT8+iattBF ; cross -> crossBF)
// ---------------------------------------------------------------------------
__global__ __launch_bounds__(256) void prep_all_k(
    const float* __restrict__ s0, const float* __restrict__ s1,
    const float* __restrict__ s2, const float* __restrict__ s3,
    const float* __restrict__ s4, const float* __restrict__ s5,
    u16* __restrict__ d0, u16* __restrict__ d1, u16* __restrict__ d2,
    u16* __restrict__ d3, u16* __restrict__ d4, u16* __restrict__ d5,
    const int* __restrict__ i_att, unsigned char* __restrict__ iattT8,
    u16* __restrict__ iattBF,
    const int* __restrict__ cross, u16* __restrict__ crossBF)
{
    const int id = blockIdx.x;
    if (id < 3072) {
        __shared__ float t[32][33];
        const float* W; u16* Wt; int N, bx, by;
        if (id < 2304) {
            int which = id / 768, local = id - which * 768;
            W = which == 0 ? s0 : (which == 1 ? s1 : s2);
            Wt = which == 0 ? d0 : (which == 1 ? d1 : d2);
            N = 1536; bx = local % 48; by = local / 48;
        } else {
            int which = (id - 2304) / 256, local = (id - 2304) % 256;
            W = which == 0 ? s3 : (which == 1 ? s4 : s5);
            Wt = which == 0 ? d3 : (which == 1 ? d4 : d5);
            N = 512; bx = local % 16; by = local / 16;
        }
        const int K = 512;
        int tx = threadIdx.x & 31, ty = threadIdx.x >> 5;
        #pragma unroll
        for (int r = ty; r < 32; r += 8)
            t[r][tx] = W[(size_t)(by * 32 + r) * N + bx * 32 + tx];
        __syncthreads();
        #pragma unroll
        for (int r = ty; r < 32; r += 8)
            Wt[(size_t)(bx * 32 + r) * K + by * 32 + tx] = f2b(t[tx][r]);
        return;
    }
    const int id2 = id - 3072;
    const int xt = id2 & 31, kt = (id2 >> 5) & 7, z = id2 >> 8;
    const int bh = z & 31;
    const int tid = threadIdx.x;
    const u16 NEG = f2b(-1e9f);
    const int sl = tid >> 7, rem = tid & 127, l = rem >> 1, nilow = rem & 1;
    const int lg = l >> 4, lr_ = l & 15;
    const int xl0 = sl * 16 + lg * 4, kl = nilow * 16 + lr_;
    if (z < 32) {
        __shared__ unsigned char t8[32][33];   // [x][k]
        const int tx = tid & 31, ty = tid >> 5;
        #pragma unroll
        for (int r = ty; r < 32; r += 8)
            t8[r][tx] = (unsigned char)(i_att[((size_t)bh * 1024 + xt * 32 + r) * 256 + kt * 32 + tx] != 0);
        __syncthreads();
        #pragma unroll
        for (int r = ty; r < 32; r += 8)
            iattT8[((size_t)bh * 256 + kt * 32 + r) * 1024 + xt * 32 + tx] = t8[tx][r];
        ushort4 o;
        o.x = t8[xl0 + 0][kl] ? NEG : (u16)0;
        o.y = t8[xl0 + 1][kl] ? NEG : (u16)0;
        o.z = t8[xl0 + 2][kl] ? NEG : (u16)0;
        o.w = t8[xl0 + 3][kl] ? NEG : (u16)0;
        size_t eb = (((size_t)bh * 64 + xt * 2 + sl) * 8 + kt) * 512 + (size_t)l * 8 + nilow * 4;
        *reinterpret_cast<ushort4*>(iattBF + eb) = o;
    } else {
        const int kg = kt * 32 + kl;
        u16 o_[4];
        #pragma unroll
        for (int j = 0; j < 4; ++j) {
            int mm = cross[((size_t)bh * 1024 + xt * 32 + xl0 + j) * 256 + kg];
            o_[j] = mm ? NEG : (u16)0;
        }
        ushort4 o; o.x = o_[0]; o.y = o_[1]; o.z = o_[2]; o.w = o_[3];
        size_t eb = (((size_t)bh * 64 + xt * 2 + sl) * 8 + kt) * 512 + (size_t)l * 8 + nilow * 4;
        *reinterpret_cast<ushort4*>(crossBF + eb) = o;
    }
}

// ---------------------------------------------------------------------------
// main orientation: block per (b,k); reads polar row once, loops 8 heads.
// ---------------------------------------------------------------------------
__global__ __launch_bounds__(256) void main_ori_k8(
    const u16* __restrict__ S, const int* __restrict__ polar,
    int* __restrict__ MO)
{
    const int blk = blockIdx.x;          // b*256 + k
    const int b = blk >> 8, k = blk & 255;
    const int tid = threadIdx.x;
    const int wave = tid >> 6, lane = tid & 63;
    const int c = tid * 4;
    int4 p4 = *reinterpret_cast<const int4*>(polar + ((size_t)b * 256 + k) * 1024 + c);
    int pp[4] = { p4.x, p4.y, p4.z, p4.w };
    #pragma unroll
    for (int j = 0; j < 4; ++j) { int p = pp[j]; pp[j] = p < 0 ? 0 : (p > 7 ? 7 : p); }
    __shared__ float sred[4][8];
    for (int h = 0; h < 8; ++h) {
        const int bh = b * 8 + h;
        ushort4 sv = *reinterpret_cast<const ushort4*>(S + ((size_t)bh * 256 + k) * 1024 + c);
        float av[4] = { fabsf(b2f(sv.x)), fabsf(b2f(sv.y)), fabsf(b2f(sv.z)), fabsf(b2f(sv.w)) };
        float bins[8] = {};
        #pragma unroll
        for (int j = 0; j < 4; ++j) {
            #pragma unroll
            for (int o = 0; o < 8; ++o) bins[o] += (pp[j] == o) ? av[j] : 0.0f;
        }
        #pragma unroll
        for (int o = 0; o < 8; ++o) bins[o] = wred_sum(bins[o]);
        if (lane == 0) {
            #pragma unroll
            for (int o = 0; o < 8; ++o) sred[wave][o] = bins[o];
        }
        __syncthreads();
        if (tid == 0) {
            int best = 0; float bv = -1.0f;
            #pragma unroll
            for (int o = 0; o < 8; ++o) {
                float s = sred[0][o] + sred[1][o] + sred[2][o] + sred[3][o];
                if (s > bv) { bv = s; best = o; }
            }
            MO[bh * 256 + k] = best;
        }
        __syncthreads();
    }
}

// ---------------------------------------------------------------------------
// Combined bias build (after MO): biasF fragment order (-1e9) + bias1 [bh,k,x] (-1e6)
// ---------------------------------------------------------------------------
__global__ __launch_bounds__(256) void bias_build_k(
    const int* __restrict__ rd, const int* __restrict__ polar,
    const int* __restrict__ att, const float* __restrict__ dis,
    const float* __restrict__ pemb, const int* __restrict__ MO,
    u16* __restrict__ biasF, u16* __restrict__ bias1)
{
    const int b = blockIdx.z;
    const int xt = blockIdx.x * 32, kt = blockIdx.y * 32;
    const int tid = threadIdx.x;
    __shared__ float dsh[528];
    __shared__ int rds[32][33];   // [x][k]
    __shared__ int pls[32][33];
    __shared__ u16 bt[32][33];    // -1e6 variant [x][k]
    for (int i = tid; i < 528; i += 256) dsh[i] = dis[i];
    const int tx = tid & 31, ty = tid >> 5;
    #pragma unroll
    for (int r = ty; r < 32; r += 8) {
        size_t src = ((size_t)b * 256 + kt + r) * 1024 + xt + tx;  // rd[b,k,x]
        rds[tx][r] = rd[src];
        int p = polar[src]; pls[tx][r] = p < 0 ? 0 : (p > 7 ? 7 : p);
    }
    float pe[8];
    #pragma unroll
    for (int o = 0; o < 8; ++o) pe[o] = pemb[o];
    __syncthreads();
    const int sl = tid >> 7, rem = tid & 127, l = rem >> 1, nilow = rem & 1;
    const int lg = l >> 4, lr_ = l & 15;
    const int xl0 = sl * 16 + lg * 4, kl = nilow * 16 + lr_;
    const int kg = kt + kl;
    const u16 NEG9 = f2b(-1e9f), NEG6 = f2b(-1e6f);
    for (int h = 0; h < 8; ++h) {
        const int bh = b * 8 + h;
        int mo = MO[bh * 256 + kg];
        u16 o9[4];
        #pragma unroll
        for (int j = 0; j < 4; ++j) {
            int xl = xl0 + j;
            int mm = att[((size_t)bh * 1024 + xt + xl) * 256 + kg];
            float v = dsh[rds[xl][kl] * 8 + h] + pe[(pls[xl][kl] - mo + 8) & 7];
            u16 vb = f2b(v);
            o9[j] = mm ? NEG9 : vb;
            bt[xl][kl] = mm ? NEG6 : vb;
        }
        size_t eb = (((size_t)bh * 64 + (xt >> 4) + sl) * 8 + (kt >> 5)) * 512 + (size_t)l * 8 + nilow * 4;
        ushort4 ov; ov.x = o9[0]; ov.y = o9[1]; ov.z = o9[2]; ov.w = o9[3];
        *reinterpret_cast<ushort4*>(biasF + eb) = ov;
        __syncthreads();
        const int k_ = tid >> 3, x4 = (tid & 7) * 4;
        ushort4 o2;
        o2.x = bt[x4 + 0][k_]; o2.y = bt[x4 + 1][k_];
        o2.z = bt[x4 + 2][k_]; o2.w = bt[x4 + 3][k_];
        *reinterpret_cast<ushort4*>(bias1 + ((size_t)bh * 256 + kt + k_) * 1024 + xt + x4) = o2;
        __syncthreads();
    }
}

// ---------------------------------------------------------------------------
// Software-pipelined 128x128 staged MFMA core. AT = float (cast fused at
// staging) or u16. Optional A2 (bf16): summed into A at staging (runtime).
// ---------------------------------------------------------------------------
template<typename AT>
__device__ __forceinline__ void gemm_core_128(
    const AT* __restrict__ A, const AT* __restrict__ A2,
    const u16* __restrict__ Wt,
    int rb, int cb, short* Asl, short* Bsl, f32x4 (&acc)[4][4])
{
    constexpr bool F32 = sizeof(AT) == 4;
    const int tid = threadIdx.x;
    const int w = tid >> 6, lane = tid & 63;
    const int lr = lane & 15, lk = (lane >> 4) * 8;
    const int wr = (w >> 1) * 64, wc = (w & 1) * 64;
    const int srow = tid >> 3, skc = (tid & 7) * 8;
    const AT* gA = A + (size_t)(rb + srow) * 512 + skc;
    const AT* gA2 = A2 ? A2 + (size_t)(rb + srow) * 512 + skc : nullptr;
    const u16* gB = Wt + (size_t)(cb + srow) * 512 + skc;
    float4 ral[4], rah[4];
    bf16x8 rab[4], rab2[4], rw[4];
    #pragma unroll
    for (int it = 0; it < 4; ++it) {
        if constexpr (F32) {
            ral[it] = *reinterpret_cast<const float4*>(gA + (size_t)it * 32 * 512);
            rah[it] = *reinterpret_cast<const float4*>(gA + (size_t)it * 32 * 512 + 4);
        } else {
            rab[it] = *reinterpret_cast<const bf16x8*>(gA + (size_t)it * 32 * 512);
            if (gA2) rab2[it] = *reinterpret_cast<const bf16x8*>(gA2 + (size_t)it * 32 * 512);
        }
        rw[it] = *reinterpret_cast<const bf16x8*>(gB + (size_t)it * 32 * 512);
    }
    for (int t = 0; t < 8; ++t) {
        #pragma unroll
        for (int it = 0; it < 4; ++it) {
            if constexpr (F32) {
                u16x8 o;
                o[0] = f2b(ral[it].x); o[1] = f2b(ral[it].y);
                o[2] = f2b(ral[it].z); o[3] = f2b(ral[it].w);
                o[4] = f2b(rah[it].x); o[5] = f2b(rah[it].y);
                o[6] = f2b(rah[it].z); o[7] = f2b(rah[it].w);
                *reinterpret_cast<u16x8*>(&Asl[(it * 32 + srow) * 72 + skc]) = o;
            } else {
                if (gA2) {
                    u16x8 o;
                    #pragma unroll
                    for (int e = 0; e < 8; ++e)
                        o[e] = f2b(b2f((u16)rab[it][e]) + b2f((u16)rab2[it][e]));
                    *reinterpret_cast<u16x8*>(&Asl[(it * 32 + srow) * 72 + skc]) = o;
                } else {
                    *reinterpret_cast<bf16x8*>(&Asl[(it * 32 + srow) * 72 + skc]) = rab[it];
                }
            }
            *reinterpret_cast<bf16x8*>(&Bsl[(it * 32 + srow) * 72 + skc]) = rw[it];
        }
        if (t < 7) {
            const int k0 = (t + 1) * 64;
            #pragma unroll
            for (int it = 0; it < 4; ++it) {
                if constexpr (F32) {
                    ral[it] = *reinterpret_cast<const float4*>(gA + k0 + (size_t)it * 32 * 512);
                    rah[it] = *reinterpret_cast<const float4*>(gA + k0 + (size_t)it * 32 * 512 + 4);
                } else {
                    rab[it] = *reinterpret_cast<const bf16x8*>(gA + k0 + (size_t)it * 32 * 512);
                    if (gA2) rab2[it] = *reinterpret_cast<const bf16x8*>(gA2 + k0 + (size_t)it * 32 * 512);
                }
                rw[it] = *reinterpret_cast<const bf16x8*>(gB + k0 + (size_t)it * 32 * 512);
            }
        }
        __syncthreads();
        #pragma unroll
        for (int ks = 0; ks < 2; ++ks) {
            bf16x8 af[4], bf_[4];
            #pragma unroll
            for (int mi = 0; mi < 4; ++mi)
                af[mi] = *reinterpret_cast<const bf16x8*>(&Asl[(wr + mi * 16 + lr) * 72 + ks * 32 + lk]);
            #pragma unroll
            for (int ni = 0; ni < 4; ++ni)
                bf_[ni] = *reinterpret_cast<const bf16x8*>(&Bsl[(wc + ni * 16 + lr) * 72 + ks * 32 + lk]);
            #pragma unroll
            for (int mi = 0; mi < 4; ++mi)
                #pragma unroll
                for (int ni = 0; ni < 4; ++ni)
                    acc[mi][ni] = mfma16(af[mi], bf_[ni], acc[mi][ni]);
        }
        __syncthreads();
    }
}

// ---------------------------------------------------------------------------
// QKV GEMM body with coalesced epilogues. q/k: restage via LDS [128][136],
// then 8 lanes cover a 128B row run (full cachelines). v: LDS transpose then
// 8-threads-per-row 16B writes.
// ---------------------------------------------------------------------------
template<typename AT>
__device__ __forceinline__ void qkv_body(
    const AT* __restrict__ A, const u16* __restrict__ Wt,
    u16* __restrict__ qb, u16* __restrict__ kb, u16* __restrict__ vt,
    int sl, int rb, int cb)
{
    __shared__ __align__(16) short Ls[2 * 128 * 72];
    short* Asl = Ls;
    short* Bsl = Ls + 128 * 72;
    f32x4 acc[4][4] = {};
    gemm_core_128<AT>(A, nullptr, Wt, rb, cb, Asl, Bsl, acc);
    const int tid = threadIdx.x;
    const int wave = tid >> 6, lane = tid & 63;
    const int lr = lane & 15, lg = lane >> 4;
    const int wr = (wave >> 1) * 64, wc = (wave & 1) * 64;
    const int seq = 1 << sl, smask = seq - 1;
    if (cb < 1024) {
        const float scl = (cb < 512) ? 0.125f : 1.0f;
        #pragma unroll
        for (int mi = 0; mi < 4; ++mi)
            #pragma unroll
            for (int ni = 0; ni < 4; ++ni) {
                int row = wr + mi * 16 + lg * 4;
                int col = wc + ni * 16 + lr;
                f32x4 v = acc[mi][ni];
                #pragma unroll
                for (int j = 0; j < 4; ++j)
                    Ls[(row + j) * 136 + col] = (short)f2b(v[j] * scl);
            }
        __syncthreads();
        u16* dst = (cb < 512) ? qb : kb;
        if (dst) {
            const int cbase = (cb < 512) ? cb : cb - 512;
            #pragma unroll
            for (int p = 0; p < 8; ++p) {
                int slot = p * 256 + tid;
                int row = slot >> 4;
                int half = (slot >> 3) & 1;
                int inner = slot & 7;
                int m = rb + row;
                int bb = m >> sl, n = m & smask;
                int cg = cbase + half * 64;
                int h = cg >> 6;
                u16x8 val = *reinterpret_cast<u16x8*>(&Ls[row * 136 + half * 64 + inner * 8]);
                *reinterpret_cast<u16x8*>(
                    &dst[(((size_t)bb * HH + h) * seq + n) * 64 + inner * 8]) = val;
            }
        }
    } else {
        #pragma unroll
        for (int mi = 0; mi < 4; ++mi)
            #pragma unroll
            for (int ni = 0; ni < 4; ++ni) {
                int col = wc + ni * 16 + lr;
                int row0 = wr + mi * 16 + lg * 4;
                f32x4 v = acc[mi][ni];
                #pragma unroll
                for (int j = 0; j < 4; ++j)
                    Ls[col * 136 + row0 + j] = (short)f2b(v[j]);
            }
        __syncthreads();
        const int bb = rb >> sl, n0 = rb & smask;
        #pragma unroll
        for (int p = 0; p < 4; ++p) {
            int slot = p * 256 + tid;
            int col = slot >> 3;
            int inner = slot & 7;
            int dg = (cb - 1024) + col;
            int h = dg >> 6, d = dg & 63;
            u16* vrow = vt + ((((size_t)bb * HH + h) * 64 + d) << sl) + n0;
            u16x8 v0 = *reinterpret_cast<u16x8*>(&Ls[col * 136 + inner * 8]);
            u16x8 v1 = *reinterpret_cast<u16x8*>(&Ls[col * 136 + 64 + inner * 8]);
            *reinterpret_cast<u16x8*>(vrow + inner * 8) = v0;
            *reinterpret_cast<u16x8*>(vrow + 64 + inner * 8) = v1;
        }
    }
}

// All 4 first-stage QKV GEMMs (f32 input, cast fused): 960 blocks, XCD swizzle
__global__ __launch_bounds__(256, 3) void gemm_qkv_all_k(
    const float* __restrict__ A0, const float* __restrict__ A1,
    const float* __restrict__ A2, const float* __restrict__ A3,
    const u16* __restrict__ W01, const u16* __restrict__ W23,
    u16* q0, u16* k0, u16* v0, u16* q1, u16* k1, u16* v1,
    u16* q2, u16* k2, u16* v2, u16* q3, u16* k3, u16* v3)
{
    const int lin = blockIdx.x;
    const int swz = (lin & 7) * 120 + (lin >> 3);
    const int x = swz % 12, y = swz / 12;
    const float* A; const u16* Wt; u16 *qb, *kb, *vt; int sl, ry;
    if (y < 32)      { A = A0; Wt = W01; qb = q0; kb = k0; vt = v0; sl = 10; ry = y; }
    else if (y < 40) { A = A1; Wt = W01; qb = q1; kb = k1; vt = v1; sl = 8;  ry = y - 32; }
    else if (y < 72) { A = A2; Wt = W23; qb = q2; kb = k2; vt = v2; sl = 10; ry = y - 40; }
    else             { A = A3; Wt = W23; qb = q3; kb = k3; vt = v3; sl = 8;  ry = y - 72; }
    qkv_body<float>(A, Wt, qb, kb, vt, sl, ry * 128, x * 128);
}

// Second-stage QKV GEMM (IKOUT, bf16 input): only k/v columns (x offset +4)
__global__ __launch_bounds__(256, 3) void gemm_qkv2_k(
    const u16* __restrict__ A, const u16* __restrict__ Wt,
    u16* kb, u16* vt)
{
    qkv_body<u16>(A, Wt, nullptr, kb, vt, 8, blockIdx.y * 128, (blockIdx.x + 4) * 128);
}

// ---------------------------------------------------------------------------
// Proj GEMM body (pipelined core, bf16 A, optional A2 summed) + bias epilogue
// ---------------------------------------------------------------------------
template<bool OUTBF>
__device__ __forceinline__ void proj_body(
    const u16* __restrict__ A, const u16* __restrict__ A2,
    const u16* __restrict__ Wt,
    const float* __restrict__ bias, float bscale, void* __restrict__ outp,
    int rb, int cb)
{
    __shared__ __align__(16) short Ls[2 * 128 * 72];
    f32x4 acc[4][4] = {};
    gemm_core_128<u16>(A, A2, Wt, rb, cb, Ls, Ls + 128 * 72, acc);
    const int tid = threadIdx.x;
    const int wave = tid >> 6, lane = tid & 63;
    const int lr = lane & 15;
    const int wr = (wave >> 1) * 64, wc = (wave & 1) * 64;
    #pragma unroll
    for (int mi = 0; mi < 4; ++mi) {
        int m0 = rb + wr + mi * 16 + (lane >> 4) * 4;
        #pragma unroll
        for (int ni = 0; ni < 4; ++ni) {
            int c = cb + wc + ni * 16 + lr;
            float bv = bscale * bias[c];
            f32x4 v = acc[mi][ni];
            #pragma unroll
            for (int j = 0; j < 4; ++j) {
                size_t o = (size_t)(m0 + j) * 512 + c;
                if (OUTBF) reinterpret_cast<u16*>(outp)[o] = f2b(v[j] + bv);
                else       reinterpret_cast<float*>(outp)[o] = v[j] + bv;
            }
        }
    }
}

// single proj (IKOUT, bf16 out)
__global__ __launch_bounds__(256, 3) void gemm_proj_bf16_k(
    const u16* __restrict__ A, const u16* __restrict__ Wt,
    const float* __restrict__ bias, float bscale, u16* __restrict__ outp)
{
    proj_body<true>(A, nullptr, Wt, bias, bscale, outp, blockIdx.y * 128, blockIdx.x * 128);
}

// final combined proj: 288 linear blocks (128 x_out [dual-A], 128 i_x_out, 32 k_out)
__global__ __launch_bounds__(256, 3) void gemm_proj3_k(
    const u16* __restrict__ A0, const u16* __restrict__ A0b,
    const u16* __restrict__ A1, const u16* __restrict__ A2,
    const u16* __restrict__ W, const u16* __restrict__ Wi2,
    const float* __restrict__ bp, const float* __restrict__ bpi2,
    float* __restrict__ o0, float* __restrict__ o1, float* __restrict__ o2)
{
    const int id = blockIdx.x;
    const u16 *A, *Ax; const u16* Wt; const float* bias; float bscale; float* outp; int x, y;
    if (id < 128)      { A = A0; Ax = A0b; Wt = W;   bias = bp;   bscale = 2.0f; outp = o0; x = id & 3; y = id >> 2; }
    else if (id < 256) { A = A1; Ax = nullptr; Wt = Wi2; bias = bpi2; bscale = 1.0f; outp = o1; x = (id - 128) & 3; y = (id - 128) >> 2; }
    else               { A = A2; Ax = nullptr; Wt = W;   bias = bp;   bscale = 1.0f; outp = o2; x = (id - 256) & 3; y = (id - 256) >> 2; }
    proj_body<false>(A, Ax, Wt, bias, bscale, outp, y * 128, x * 128);
}

// ---------------------------------------------------------------------------
// Paired wide scores with coalesced S epilogue via LDS restage.
// z<32 -> (KQ,KX)->SPa ; else (IKQ,IK)->SPb. R=256,C=1024.
// ---------------------------------------------------------------------------
__global__ __launch_bounds__(256, 4) void scores_pair_k(
    const u16* __restrict__ A1, const u16* __restrict__ B1, u16* __restrict__ S1,
    const u16* __restrict__ A2, const u16* __restrict__ B2, u16* __restrict__ S2)
{
    __shared__ __align__(16) short Ls[2 * 128 * 72];
    short* As = Ls;
    short* Bs = Ls + 128 * 72;
    const int z = blockIdx.z, bh = z & 31;
    const u16* Aq = (z < 32) ? A1 : A2;
    const u16* Bk = (z < 32) ? B1 : B2;
    u16* S = (z < 32) ? S1 : S2;
    const int tid = threadIdx.x;
    const int wave = tid >> 6, lane = tid & 63;
    const int lr = lane & 15, lg = lane >> 4, lk = lg * 8;
    const int rb = blockIdx.y * 128, cb = blockIdx.x * 128;
    const int wr = (wave >> 1) * 64, wc = (wave & 1) * 64;
    const u16* Ap = Aq + (size_t)bh * 256 * 64;
    const u16* Bp = Bk + (size_t)bh * 1024 * 64;
    const int srow = tid >> 3, skc = (tid & 7) * 8;
    #pragma unroll
    for (int it = 0; it < 4; ++it) {
        int row = it * 32 + srow;
        *reinterpret_cast<bf16x8*>(&As[row * 72 + skc]) =
            *reinterpret_cast<const bf16x8*>(Ap + (size_t)(rb + row) * 64 + skc);
        *reinterpret_cast<bf16x8*>(&Bs[row * 72 + skc]) =
            *reinterpret_cast<const bf16x8*>(Bp + (size_t)(cb + row) * 64 + skc);
    }
    __syncthreads();
    f32x4 acc[4][4] = {};
    #pragma unroll
    for (int ks = 0; ks < 2; ++ks) {
        bf16x8 af[4], bf_[4];
        #pragma unroll
        for (int mi = 0; mi < 4; ++mi)
            af[mi] = *reinterpret_cast<const bf16x8*>(&As[(wr + mi * 16 + lr) * 72 + ks * 32 + lk]);
        #pragma unroll
        for (int ni = 0; ni < 4; ++ni)
            bf_[ni] = *reinterpret_cast<const bf16x8*>(&Bs[(wc + ni * 16 + lr) * 72 + ks * 32 + lk]);
        #pragma unroll
        for (int mi = 0; mi < 4; ++mi)
            #pragma unroll
            for (int ni = 0; ni < 4; ++ni)
                acc[mi][ni] = mfma16(af[mi], bf_[ni], acc[mi][ni]);
    }
    __syncthreads();   // all LDS reads done -> reuse Ls as [128][136] epilogue buffer
    #pragma unroll
    for (int mi = 0; mi < 4; ++mi)
        #pragma unroll
        for (int ni = 0; ni < 4; ++ni) {
            int row = wr + mi * 16 + lg * 4;
            int col = wc + ni * 16 + lr;
            f32x4 v = acc[mi][ni];
            #pragma unroll
            for (int j = 0; j < 4; ++j)
                Ls[(row + j) * 136 + col] = (short)f2b(v[j]);
        }
    __syncthreads();
    #pragma unroll
    for (int p = 0; p < 8; ++p) {
        int slot = p * 256 + tid;
        int row = slot >> 4;
        int chunk = slot & 15;
        u16x8 val = *reinterpret_cast<u16x8*>(&Ls[row * 136 + chunk * 8]);
        *reinterpret_cast<u16x8*>(
            &S[((size_t)bh * 256 + rb + row) * 1024 + cb + chunk * 8]) = val;
    }
}

// ---------------------------------------------------------------------------
// Fused softmax+PV: softmax(S+bias)·V computed as (exp(S+b-m)·V)·(1/Σ).
// Pass1: row max. Pass2: MFMA with unnormalized exp + row-sum alongside.
// Epilogue: scale by 1/Σ (per-row via shfl), coalesced write.
// z=0: (SPa,bias1,VXt)->KMb ; z=1: (SPb,iattT8,IVt)->KMb2
// ---------------------------------------------------------------------------
template<bool HASB>
__device__ __forceinline__ void pv_fused_body(
    const u16* __restrict__ P, const u16* __restrict__ BIAS,
    const unsigned char* __restrict__ MSK,
    const u16* __restrict__ V, u16* __restrict__ out, short* Ps)
{
    const int tid = threadIdx.x;
    const int wave = tid >> 6, lane = tid & 63;
    const int lr = lane & 15, lg = lane >> 4, lk = lg * 8;
    const int bh = blockIdx.y, b = bh >> 3, h = bh & 7;
    const int rb = blockIdx.x * 64;
    const int wr = wave * 16;
    const size_t rowg = (size_t)bh * 256 + rb + wr + lr;   // global S row
    const u16* Prow = P + rowg * 1024;
    const u16* Brow = HASB ? BIAS + rowg * 1024 : nullptr;
    const unsigned char* Mrow = HASB ? nullptr : MSK + rowg * 1024;
    const u16* Vb = V + (size_t)bh * 64 * 1024;

    // pass 1: row max over this lane's 256 elements, then across the 4 lanes
    float m = -3.4e38f;
    for (int c0 = 0; c0 < 1024; c0 += 64) {
        #pragma unroll
        for (int ks = 0; ks < 2; ++ks) {
            const int cc = c0 + ks * 32 + lk;
            bf16x8 sv = *reinterpret_cast<const bf16x8*>(Prow + cc);
            if (HASB) {
                bf16x8 bv = *reinterpret_cast<const bf16x8*>(Brow + cc);
                #pragma unroll
                for (int e = 0; e < 8; ++e)
                    m = fmaxf(m, b2f((u16)sv[e]) + b2f((u16)bv[e]));
            } else {
                u64 mk = *reinterpret_cast<const u64*>(Mrow + cc);
                #pragma unroll
                for (int e = 0; e < 8; ++e) {
                    float s = ((mk >> (e * 8)) & 0xFFull) ? -1e9f : b2f((u16)sv[e]);
                    m = fmaxf(m, s);
                }
            }
        }
    }
    m = fmaxf(m, __shfl_xor(m, 16, 64));
    m = fmaxf(m, __shfl_xor(m, 32, 64));

    // pass 2: MFMA with unnormalized e = exp(s-m); accumulate row sum
    f32x4 acc[4] = {};
    float sum = 0.0f;
    for (int c0 = 0; c0 < 1024; c0 += 64) {
        #pragma unroll
        for (int ks = 0; ks < 2; ++ks) {
            const int cc = c0 + ks * 32 + lk;
            bf16x8 sv = *reinterpret_cast<const bf16x8*>(Prow + cc);
            bf16x8 ap;
            if (HASB) {
                bf16x8 bv = *reinterpret_cast<const bf16x8*>(Brow + cc);
                #pragma unroll
                for (int e = 0; e < 8; ++e) {
                    float ev = __expf(b2f((u16)sv[e]) + b2f((u16)bv[e]) - m);
                    sum += ev;
                    ap[e] = (short)f2b(ev);
                }
            } else {
                u64 mk = *reinterpret_cast<const u64*>(Mrow + cc);
                #pragma unroll
                for (int e = 0; e < 8; ++e) {
                    float s = ((mk >> (e * 8)) & 0xFFull) ? -1e9f : b2f((u16)sv[e]);
                    float ev = __expf(s - m);
                    sum += ev;
                    ap[e] = (short)f2b(ev);
                }
            }
            #pragma unroll
            for (int ni = 0; ni < 4; ++ni) {
                bf16x8 vv = *reinterpret_cast<const bf16x8*>(
                    Vb + (size_t)(ni * 16 + lr) * 1024 + cc);
                acc[ni] = mfma16(ap, vv, acc[ni]);
            }
        }
    }
    sum += __shfl_xor(sum, 16, 64);
    sum += __shfl_xor(sum, 32, 64);
    const float inv = 1.0f / sum;
    // inv for output row (lg*4+j) lives in lane (lg*4+j) (its lr == that row)
    float invj[4];
    #pragma unroll
    for (int j = 0; j < 4; ++j) invj[j] = __shfl(inv, lg * 4 + j, 64);

    short* myP = &Ps[wave * 16 * 72];
    #pragma unroll
    for (int ni = 0; ni < 4; ++ni) {
        int d = ni * 16 + lr;
        f32x4 v = acc[ni];
        #pragma unroll
        for (int j = 0; j < 4; ++j)
            myP[(lg * 4 + j) * 72 + d] = (short)f2b(v[j] * invj[j]);
    }
    #pragma unroll
    for (int p = 0; p < 2; ++p) {
        int slot = p * 64 + lane;
        int rloc = slot >> 3;
        int inner = slot & 7;
        int r0 = rb + wr + rloc;
        u16x8 val = *reinterpret_cast<u16x8*>(&myP[rloc * 72 + inner * 8]);
        *reinterpret_cast<u16x8*>(
            &out[((size_t)(b * 256 + r0)) * 512 + h * 64 + inner * 8]) = val;
    }
}

__global__ __launch_bounds__(256, 4) void pv_fused_k(
    const u16* __restrict__ P1, const u16* __restrict__ B1,
    const u16* __restrict__ V1, u16* __restrict__ o1,
    const u16* __restrict__ P2, const unsigned char* __restrict__ M2,
    const u16* __restrict__ V2, u16* __restrict__ o2)
{
    __shared__ __align__(16) short Ps[4 * 16 * 72];
    if (blockIdx.z == 0)
        pv_fused_body<true>(P1, B1, nullptr, V1, o1, Ps);
    else
        pv_fused_body<false>(P2, nullptr, M2, V2, o2, Ps);
}

// ---------------------------------------------------------------------------
// Merged fused attention: 1536 blocks.
//  [0,512)    : branch2 src0 (Q, KK, KVt, biasF)   -> XMb
//  [512,1024) : branch2 src1 (Q, IKK, IKVt, crossBF)-> XMc
//  [1024,1536): branch3     (IQ, K2K, K2Vt, iattBF) -> XMb2
// 64 x-rows/block, 4 waves, wave owns 16 rows, zero barriers.
// ---------------------------------------------------------------------------
__global__ __launch_bounds__(256, 4) void attn_all_k(
    const u16* __restrict__ Q0, const u16* __restrict__ IQ0,
    const u16* __restrict__ K1, const u16* __restrict__ V1t,
    const u16* __restrict__ B1F, u16* __restrict__ out1,
    const u16* __restrict__ K2, const u16* __restrict__ V2t,
    const u16* __restrict__ B2F, u16* __restrict__ out2,
    const u16* __restrict__ K3, const u16* __restrict__ V3t,
    const u16* __restrict__ B3F, u16* __restrict__ out3)
{
    const int tid = threadIdx.x;
    const int w = tid >> 6, lane = tid & 63;
    const int lr = lane & 15, lg = lane >> 4, lk = lg * 8;
    int lin = blockIdx.x;
    const u16 *Qp, *Kp, *Vp, *BF; u16* outm;
    if (lin < 512)        { Qp = Q0;  Kp = K1; Vp = V1t; BF = B1F; outm = out1; }
    else if (lin < 1024)  { Qp = Q0;  Kp = K2; Vp = V2t; BF = B2F; outm = out2; lin -= 512; }
    else                  { Qp = IQ0; Kp = K3; Vp = V3t; BF = B3F; outm = out3; lin -= 1024; }
    const int xcd = lin & 7, idx = lin >> 3;
    const int bh = xcd * 4 + (idx & 3);
    const int rb = (idx >> 2) * 64;
    const int b = bh >> 3, h = bh & 7;
    const int wr = w * 16;
    const int strip = (rb >> 4) + w;

    __shared__ __align__(16) short Ps[4 * 16 * 264];   // per-wave scratch
    short* myP = &Ps[w * 16 * 264];

    bf16x8 qf0, qf1;
    {
        const u16* Qb = Qp + ((size_t)bh * 1024 + rb + wr + lr) * 64;
        qf0 = *reinterpret_cast<const bf16x8*>(Qb + lk);
        qf1 = *reinterpret_cast<const bf16x8*>(Qb + 32 + lk);
    }

    // bias prefetch (fragment order): 8 x 16B fully-coalesced loads
    bf16x8 breg[8];
    {
        const u16* bb = BF + (((size_t)bh * 64 + strip) * 8) * 512 + (size_t)lane * 8;
        #pragma unroll
        for (int itp = 0; itp < 8; ++itp)
            breg[itp] = *reinterpret_cast<const bf16x8*>(bb + (size_t)itp * 512);
    }
    // scores: 16 rows x 256 cols per wave; K direct from global (L2)
    const u16* Kb = Kp + (size_t)bh * 256 * 64;
    f32x4 acc[16];
    #pragma unroll
    for (int ni = 0; ni < 16; ++ni) acc[ni] = (f32x4){0.f, 0.f, 0.f, 0.f};
    #pragma unroll
    for (int ni = 0; ni < 16; ++ni) {
        bf16x8 b0 = *reinterpret_cast<const bf16x8*>(Kb + (size_t)(ni * 16 + lr) * 64 + lk);
        acc[ni] = mfma16(qf0, b0, acc[ni]);
    }
    #pragma unroll
    for (int ni = 0; ni < 16; ++ni) {
        bf16x8 b1 = *reinterpret_cast<const bf16x8*>(Kb + (size_t)(ni * 16 + lr) * 64 + 32 + lk);
        acc[ni] = mfma16(qf1, b1, acc[ni]);
    }
    // bias from regs + in-wave softmax
    float mx[4] = { -3.4e38f, -3.4e38f, -3.4e38f, -3.4e38f };
    #pragma unroll
    for (int ni = 0; ni < 16; ++ni) {
        const bf16x8 br = breg[ni >> 1];
        #pragma unroll
        for (int j = 0; j < 4; ++j) {
            float v = acc[ni][j] + b2f((u16)br[(ni & 1) * 4 + j]);
            acc[ni][j] = v;
            mx[j] = fmaxf(mx[j], v);
        }
    }
    #pragma unroll
    for (int j = 0; j < 4; ++j) {
        #pragma unroll
        for (int o = 1; o < 16; o <<= 1) mx[j] = fmaxf(mx[j], __shfl_xor(mx[j], o, 64));
    }
    float sm[4] = {};
    #pragma unroll
    for (int ni = 0; ni < 16; ++ni) {
        #pragma unroll
        for (int j = 0; j < 4; ++j) {
            float e = __expf(acc[ni][j] - mx[j]);
            acc[ni][j] = e;
            sm[j] += e;
        }
    }
    #pragma unroll
    for (int j = 0; j < 4; ++j) {
        #pragma unroll
        for (int o = 1; o < 16; o <<= 1) sm[j] += __shfl_xor(sm[j], o, 64);
        sm[j] = 1.0f / sm[j];
    }
    // P to wave-local LDS (in-wave transpose), then PV with V from global
    #pragma unroll
    for (int ni = 0; ni < 16; ++ni)
        #pragma unroll
        for (int j = 0; j < 4; ++j)
            myP[(lg * 4 + j) * 264 + ni * 16 + lr] = (short)f2b(acc[ni][j] * sm[j]);
    f32x4 acc2[4] = {};
    #pragma unroll
    for (int kc = 0; kc < 8; ++kc) {
        bf16x8 ap = *reinterpret_cast<const bf16x8*>(&myP[lr * 264 + kc * 32 + lk]);
        #pragma unroll
        for (int ni = 0; ni < 4; ++ni) {
            bf16x8 vv = *reinterpret_cast<const bf16x8*>(
                Vp + ((size_t)bh * 64 + ni * 16 + lr) * 256 + kc * 32 + lk);
            acc2[ni] = mfma16(ap, vv, acc2[ni]);
        }
    }
    // coalesced epilogue: restage 16x64 tile (stride 72), 8 lanes per 128B row
    #pragma unroll
    for (int ni = 0; ni < 4; ++ni) {
        int d = ni * 16 + lr;
        f32x4 v = acc2[ni];
        #pragma unroll
        for (int j = 0; j < 4; ++j)
            myP[(lg * 4 + j) * 72 + d] = (short)f2b(v[j]);
    }
    #pragma unroll
    for (int p = 0; p < 2; ++p) {
        int slot = p * 64 + lane;
        int rloc = slot >> 3;
        int inner = slot & 7;
        int row = rb + wr + rloc;
        u16x8 val = *reinterpret_cast<u16x8*>(&myP[rloc * 72 + inner * 8]);
        *reinterpret_cast<u16x8*>(
            &outm[((size_t)(b * 1024 + row)) * 512 + h * 64 + inner * 8]) = val;
    }
}

// ---------------------------------------------------------------------------
extern "C" void kernel_launch(void* const* d_in, const int* in_sizes, int n_in,
                              void* d_out, int out_size, void* d_ws, size_t ws_size,
                              hipStream_t stream)
{
    const float* x        = (const float*)d_in[0];
    const float* kernal   = (const float*)d_in[1];
    const float* i_x      = (const float*)d_in[2];
    const float* i_kernal = (const float*)d_in[3];
    const int*   rd       = (const int*)d_in[4];
    const int*   polar    = (const int*)d_in[5];
    const int*   att      = (const int*)d_in[6];
    const int*   i_att    = (const int*)d_in[7];
    const int*   cross    = (const int*)d_in[8];
    const float* Wqkv     = (const float*)d_in[9];
    const float* Wqkv_i   = (const float*)d_in[10];
    const float* Wqkv_i2  = (const float*)d_in[11];
    const float* Wproj    = (const float*)d_in[12];
    const float* bproj    = (const float*)d_in[13];
    const float* Wproj_i  = (const float*)d_in[14];
    const float* bproj_i  = (const float*)d_in[15];
    const float* Wproj_i2 = (const float*)d_in[16];
    const float* bproj_i2 = (const float*)d_in[17];
    const float* dis      = (const float*)d_in[18];
    const float* pemb     = (const float*)d_in[19];

    float* out = (float*)d_out;
    float* x_out   = out;
    float* k_out   = out + (size_t)BB * XLL * DIMM;
    float* i_x_out = k_out + (size_t)BB * KLL * DIMM;

    char* ws = (char*)d_ws;
    size_t off = 0;
    auto alloc = [&](size_t bytes) { void* p = ws + off; off += (bytes + 255) & ~(size_t)255; return p; };

    const size_t NAX = (size_t)BB * XLL * DIMM;
    const size_t NAK = (size_t)BB * KLL * DIMM;
    const size_t NHX = (size_t)BHH * XLL * HEADD;
    const size_t NHK = (size_t)BHH * KLL * HEADD;
    const size_t NS  = (size_t)BHH * KLL * XLL;

    u16* WqkvT    = (u16*)alloc((size_t)1536 * 512 * 2);
    u16* WqkvIT   = (u16*)alloc((size_t)1536 * 512 * 2);
    u16* WqkvI2T  = (u16*)alloc((size_t)1536 * 512 * 2);
    u16* WprojT   = (u16*)alloc((size_t)512 * 512 * 2);
    u16* WprojIT  = (u16*)alloc((size_t)512 * 512 * 2);
    u16* WprojI2T = (u16*)alloc((size_t)512 * 512 * 2);
    u16* Q    = (u16*)alloc(NHX * 2);
    u16* KX   = (u16*)alloc(NHX * 2);
    u16* VXt  = (u16*)alloc(NHX * 2);
    u16* IQ   = (u16*)alloc(NHX * 2);
    u16* IK   = (u16*)alloc(NHX * 2);
    u16* IVt  = (u16*)alloc(NHX * 2);
    u16* KQ   = (u16*)alloc(NHK * 2);
    u16* KK   = (u16*)alloc(NHK * 2);
    u16* KVt  = (u16*)alloc(NHK * 2);
    u16* IKQ  = (u16*)alloc(NHK * 2);
    u16* IKK  = (u16*)alloc(NHK * 2);
    u16* IKVt = (u16*)alloc(NHK * 2);
    u16* K2K  = (u16*)alloc(NHK * 2);
    u16* K2Vt = (u16*)alloc(NHK * 2);
    u16* SPa  = (u16*)alloc(NS * 2);
    u16* SPb  = (u16*)alloc(NS * 2);
    u16* KMb  = (u16*)alloc(NAK * 2);
    u16* KMb2 = (u16*)alloc(NAK * 2);
    u16* XMb  = (u16*)alloc(NAX * 2);
    u16* XMb2 = (u16*)alloc(NAX * 2);
    u16* XMc  = (u16*)alloc(NAX * 2);
    u16* IKOUTb = (u16*)alloc(NAK * 2);
    u16* biasF = (u16*)alloc(NS * 2);
    u16* bias1 = (u16*)alloc(NS * 2);
    u16* crossBF = (u16*)alloc(NS * 2);
    u16* iattBF  = (u16*)alloc(NS * 2);
    unsigned char* iattT8 = (unsigned char*)alloc(NS);
    int* MO   = (int*)alloc((size_t)BHH * KLL * 4);

    dim3 blk(256);

    // 1. merged prep (weight transposes + mask conversions)
    prep_all_k<<<dim3(19456), blk, 0, stream>>>(
        Wqkv, Wqkv_i, Wqkv_i2, Wproj, Wproj_i, Wproj_i2,
        WqkvT, WqkvIT, WqkvI2T, WprojT, WprojIT, WprojI2T,
        i_att, iattT8, iattBF, cross, crossBF);

    // 2. all first-stage QKV GEMMs (cast fused, q pre-scaled), XCD-swizzled
    gemm_qkv_all_k<<<dim3(960), blk, 0, stream>>>(
        x, kernal, i_x, i_kernal, WqkvT, WqkvIT,
        Q, KX, VXt, KQ, KK, KVt, IQ, IK, IVt, IKQ, IKK, IKVt);

    // 3. wide scores (branch1 + branch3)
    scores_pair_k<<<dim3(8, 2, 64), blk, 0, stream>>>(KQ, KX, SPa, IKQ, IK, SPb);
    // 4. main orientation + bias builds
    main_ori_k8<<<dim3(BB * KLL), blk, 0, stream>>>(SPa, polar, MO);
    bias_build_k<<<dim3(32, 8, BB), blk, 0, stream>>>(rd, polar, att, dis, pemb, MO, biasF, bias1);
    // 5+6. fused softmax+PV (softmax folded into PV via linearity)
    pv_fused_k<<<dim3(4, 32, 2), blk, 0, stream>>>(
        SPa, bias1, VXt, KMb, SPb, iattT8, IVt, KMb2);
    // 7. IKOUT proj (bf16) + second qkv (k/v columns only)
    gemm_proj_bf16_k<<<dim3(4, 8), blk, 0, stream>>>(KMb2, WprojIT, bproj_i, 1.0f, IKOUTb);
    gemm_qkv2_k<<<dim3(8, 8), blk, 0, stream>>>(IKOUTb, WqkvI2T, K2K, K2Vt);
    // 8. all three fused attentions in one launch (1536 blocks)
    attn_all_k<<<dim3(1536), blk, 0, stream>>>(
        Q, IQ, KK, KVt, biasF, XMb, IKK, IKVt, crossBF, XMc,
        K2K, K2Vt, iattBF, XMb2);
    // 9. final combined projections (x_out = (XMb+XMc)@W, i_x_out, k_out)
    gemm_proj3_k<<<dim3(288), blk, 0, stream>>>(
        XMb, XMc, XMb2, KMb, WprojT, WprojI2T, bproj, bproj_i2, x_out, i_x_out, k_out);

    (void)in_sizes; (void)n_in; (void)out_size; (void)ws_size;
}